// Round 1
// baseline (265.029 us; speedup 1.0000x reference)
//
#include <hip/hip_runtime.h>
#include <math.h>

// Problem constants (B=2, L=2048, H=2048, K=H/NH=128)
#define B_ 2
#define L_ 2048
#define H_ 2048
#define KD_ 128
#define SCALE_ 0.08838834764831845f  // 128^-0.5
#define EPS_ 1e-5f
#define K2_ 4096                     // concat-K for the dual output GEMM

typedef __bf16 bf16x8 __attribute__((ext_vector_type(8)));
typedef float f32x4 __attribute__((ext_vector_type(4)));

static __device__ __forceinline__ float sigmoidf_(float z) {
    return 1.0f / (1.0f + __expf(-z));
}

static __device__ __forceinline__ unsigned short f2bf(float f) {
    unsigned int u = __float_as_uint(f);
    unsigned int r = (u + 0x7fffu + ((u >> 16) & 1u)) >> 16;
    return (unsigned short)r;
}

static __device__ __forceinline__ float bf2f(unsigned short s) {
    return __uint_as_float(((unsigned int)s) << 16);
}

// async global->LDS, 16B per lane; lds base must be wave-uniform
#define ASYNC_COPY16(gsrc, ldst)                                             \
    __builtin_amdgcn_global_load_lds(                                        \
        (const __attribute__((address_space(1))) unsigned int*)(gsrc),       \
        (__attribute__((address_space(3))) unsigned int*)(ldst), 16, 0, 0)

// raw barrier with compiler memory fence (no vmcnt drain, unlike __syncthreads)
#define BAR()                                                                \
    do {                                                                     \
        asm volatile("" ::: "memory");                                       \
        __builtin_amdgcn_s_barrier();                                        \
        asm volatile("" ::: "memory");                                       \
    } while (0)

// ---------------------------------------------------------------------------
// Kernel 0 (merged prep): jobA cast x->bf16 (Abuf x-half) | jobB cast
// [Wq|Wk]->bf16 + zero rrms_acc | jobC cast [Wog|Wig]->bf16 (Bbuf).
// ---------------------------------------------------------------------------
#define JOBA_BLKS 4096   // 1048576 groups of 8
#define JOBB_BLKS 256    // 65536 groups
#define JOBC_BLKS 4096   // 1048576 groups

__global__ __launch_bounds__(256) void prep_all(
    const float* __restrict__ x, const float* __restrict__ Wq,
    const float* __restrict__ Wk, const float* __restrict__ Wog,
    const float* __restrict__ Wig, unsigned short* __restrict__ Abuf,
    unsigned short* __restrict__ Wqk, unsigned short* __restrict__ Bbuf,
    float* __restrict__ rrms_acc)
{
    const int blk = blockIdx.x;
    const float* src;
    unsigned short* dst;
    if (blk < JOBA_BLKS) {
        size_t i = (size_t)blk * 256 + threadIdx.x;
        size_t m = i >> 8, c8 = (i & 255) * 8;
        src = x + m * H_ + c8;
        dst = Abuf + m * K2_ + H_ + c8;
    } else if (blk < JOBA_BLKS + JOBB_BLKS) {
        size_t i = (size_t)(blk - JOBA_BLKS) * 256 + threadIdx.x;
        if (i < 4096) rrms_acc[i] = 0.f;
        const size_t half = (size_t)KD_ * H_ / 8;   // 32768
        src = ((i < half) ? Wq : Wk) + ((i < half) ? i : i - half) * 8;
        dst = Wqk + i * 8;
    } else {
        size_t i = (size_t)(blk - JOBA_BLKS - JOBB_BLKS) * 256 + threadIdx.x;
        const size_t half = (size_t)H_ * H_ / 8;    // 524288
        size_t j = (i < half) ? i : i - half;
        size_t n = j >> 8, c8 = (j & 255) * 8;
        src = ((i < half) ? Wog : Wig) + n * H_ + c8;
        dst = Bbuf + n * K2_ + ((i < half) ? 0 : H_) + c8;
    }
    float4 v0 = *(const float4*)src;
    float4 v1 = *(const float4*)(src + 4);
    ushort4 a, b;
    a.x = f2bf(v0.x); a.y = f2bf(v0.y); a.z = f2bf(v0.z); a.w = f2bf(v0.w);
    b.x = f2bf(v1.x); b.y = f2bf(v1.y); b.z = f2bf(v1.z); b.w = f2bf(v1.w);
    *(ushort4*)dst = a;
    *(ushort4*)(dst + 4) = b;
}

// ---------------------------------------------------------------------------
// Kernel 1: qk projection GEMM via MFMA, split-K, XOR-swizzled LDS.
// A = x bf16 (Abuf x-half, row stride K2_), B = Wqk [256][2048] bf16.
// M=4096, N=256, K=2048 split into 4 slices of 512. Partials fp32 [4][4096][256].
// ---------------------------------------------------------------------------
__global__ __launch_bounds__(256) void qk_proj_mfma(
    const unsigned short* __restrict__ Abuf,
    const unsigned short* __restrict__ Wqk,
    float* __restrict__ partial)
{
    __shared__ alignas(16) unsigned short As[128 * 64];
    __shared__ alignas(16) unsigned short Bs[128 * 64];
    const int tid  = threadIdx.x;
    const int wave = tid >> 6;
    const int lane = tid & 63;
    const int m0 = blockIdx.x * 128;
    const int n0 = blockIdx.y * 128;
    const int kz = blockIdx.z * 512;
    const int wm = (wave >> 1) * 64;
    const int wn = (wave & 1) * 64;

    f32x4 acc[4][4] = {};

    const int se  = lane * 8;
    const int ldsbase = (wave * 4) * 512;
    const int frow = lane & 15;
    const int fk   = (lane >> 4) * 8;
    const int gswz = (((lane & 7) ^ (lane >> 3)) << 3);  // staging src column
    const int rswz = ((lane & 7) << 3);                  // fragment read XOR

    for (int k0 = kz; k0 < kz + 512; k0 += 64) {
        #pragma unroll
        for (int it = 0; it < 4; ++it) {
            int e = ldsbase + it * 512 + se;
            int r = e >> 6;
            const unsigned short* ga =
                Abuf + (size_t)(m0 + r) * K2_ + H_ + k0 + gswz;
            ASYNC_COPY16(ga, &As[e]);
            const unsigned short* gb = Wqk + (size_t)(n0 + r) * H_ + k0 + gswz;
            ASYNC_COPY16(gb, &Bs[e]);
        }
        __syncthreads();
        #pragma unroll
        for (int ksub = 0; ksub < 2; ++ksub) {
            bf16x8 af[4], bf[4];
            #pragma unroll
            for (int i = 0; i < 4; ++i)
                af[i] = *(const bf16x8*)(As + (wm + i * 16 + frow) * 64 +
                                         ((ksub * 32 + fk) ^ rswz));
            #pragma unroll
            for (int j = 0; j < 4; ++j)
                bf[j] = *(const bf16x8*)(Bs + (wn + j * 16 + frow) * 64 +
                                         ((ksub * 32 + fk) ^ rswz));
            #pragma unroll
            for (int i = 0; i < 4; ++i)
                #pragma unroll
                for (int j = 0; j < 4; ++j)
                    acc[i][j] = __builtin_amdgcn_mfma_f32_16x16x32_bf16(
                        af[i], bf[j], acc[i][j], 0, 0, 0);
        }
        __syncthreads();
    }

    float* pz = partial + (size_t)blockIdx.z * 4096 * 256;
    #pragma unroll
    for (int i = 0; i < 4; ++i) {
        #pragma unroll
        for (int reg = 0; reg < 4; ++reg) {
            int m = m0 + wm + i * 16 + (lane >> 4) * 4 + reg;
            #pragma unroll
            for (int j = 0; j < 4; ++j) {
                int n = n0 + wn + j * 16 + (lane & 15);
                pz[(size_t)m * 256 + n] = acc[i][j][reg];
            }
        }
    }
}

// ---------------------------------------------------------------------------
// Kernel 2 (fused): split-K reduce + epilogue + chunk-local gate scan +
// chunk-referenced bf16 scaling.
// ---------------------------------------------------------------------------
__global__ __launch_bounds__(256) void scan_scale_kernel(
    const float* __restrict__ partial,
    unsigned short* __restrict__ qt_b, unsigned short* __restrict__ kA_b,
    unsigned short* __restrict__ kB_b)
{
    const int c = blockIdx.x, b = blockIdx.y;
    const int kd = blockIdx.z * 32 + (threadIdx.x & 31);
    const int rg = threadIdx.x >> 5;              // 0..7
    const size_t stride = (size_t)4096 * 256;
    const int row0 = b * L_ + c * 64 + rg * 8;

    float qv[8], kv[8], gp[8];
    float run = 0.f;
    #pragma unroll
    for (int j = 0; j < 8; ++j) {
        size_t off = (size_t)(row0 + j) * 256;
        float sq = partial[off + kd] + partial[stride + off + kd]
                 + partial[2 * stride + off + kd] + partial[3 * stride + off + kd];
        float sk = partial[off + 128 + kd] + partial[stride + off + 128 + kd]
                 + partial[2 * stride + off + 128 + kd]
                 + partial[3 * stride + off + 128 + kd];
        float ksv = sigmoidf_(sk);
        qv[j] = sq * sigmoidf_(sq) * SCALE_;
        kv[j] = ksv;
        run += -log1pf(__expf(ksv));   // g_t in (-1.3133, -0.6931)
        gp[j] = run;
    }
    __shared__ float s_seg[8][32];
    s_seg[rg][threadIdx.x & 31] = run;
    __syncthreads();
    float base = 0.f, total = 0.f;
    #pragma unroll
    for (int r = 0; r < 8; ++r) {
        float v = s_seg[r][threadIdx.x & 31];
        base += (r < rg) ? v : 0.f;
        total += v;
    }
    #pragma unroll
    for (int j = 0; j < 8; ++j) {
        float s = base + gp[j];        // in [-84.05, -0.69]: exp in fp32 range
        size_t idx = (size_t)(row0 + j) * KD_ + kd;
        qt_b[idx] = f2bf(qv[j] * __expf(s));
        kA_b[idx] = f2bf(kv[j] * __expf(-s));
        kB_b[idx] = f2bf(kv[j] * __expf(total - s));
    }
}

// ---------------------------------------------------------------------------
// Kernel 3a: P = qt . k~^T, computed ONCE per (chunk, batch) with causal-band
// mask; written bf16 to Pbuf[cb][64 q][128 keys].
// ---------------------------------------------------------------------------
__global__ __launch_bounds__(256) void p_kernel(
    const unsigned short* __restrict__ qt_b,
    const unsigned short* __restrict__ kA_b,
    const unsigned short* __restrict__ kB_b,
    unsigned short* __restrict__ Pbuf)
{
    const int c = blockIdx.x, b = blockIdx.y;
    const int tid = threadIdx.x;
    const int w = tid >> 6, l = tid & 63;
    const int lr = l & 15, lq = l >> 4;
    const int q0 = c * 64;
    const size_t rowbase = (size_t)b * L_;

    bf16x8 aq[4];
    {
        const unsigned short* qrow = qt_b + (rowbase + q0 + 16 * w + lr) * KD_;
        #pragma unroll
        for (int kt = 0; kt < 4; ++kt)
            aq[kt] = *(const bf16x8*)(qrow + kt * 32 + lq * 8);
    }
    unsigned short* pout = Pbuf + (size_t)(b * 32 + c) * 64 * 128;
    #pragma unroll
    for (int jt = 0; jt < 8; ++jt) {
        f32x4 p = {};
        const int si = jt * 16 + lr;          // window key index 0..127
        const bool prev = (jt < 4);
        const bool dead = (c == 0 && prev);
        if (!dead) {
            int kp = prev ? (q0 - 64 + si) : (q0 + si - 64);
            const unsigned short* kb = (prev ? kB_b : kA_b) + (rowbase + kp) * KD_;
            #pragma unroll
            for (int kt = 0; kt < 4; ++kt) {
                bf16x8 bk = *(const bf16x8*)(kb + kt * 32 + lq * 8);
                p = __builtin_amdgcn_mfma_f32_16x16x32_bf16(aq[kt], bk, p, 0, 0, 0);
            }
        }
        #pragma unroll
        for (int reg = 0; reg < 4; ++reg) {
            int ti = 16 * w + lq * 4 + reg;   // q row 0..63
            bool keep = !dead && (si <= ti + 64);
            pout[ti * 128 + si] = keep ? f2bf(p[reg]) : (unsigned short)0;
        }
    }
}

// ---------------------------------------------------------------------------
// Kernel 3b: O = P @ V. Stages V transposed in LDS; P read from global
// (L2-hot, 1 MB). Writes bf16 o into Abuf o-half + rrms atomics.
// ---------------------------------------------------------------------------
#define SV_ 130   // Vt row stride (elems)

__global__ __launch_bounds__(256) void pv_kernel(
    const unsigned short* __restrict__ Pbuf,
    unsigned short* Abuf,          // reads x-half (cols 2048+), writes o-half
    float* __restrict__ rrms_acc)
{
    const int c  = blockIdx.x;   // chunk 0..31
    const int b  = blockIdx.y;
    const int vt = blockIdx.z;   // 0..15
    const int tid = threadIdx.x;
    const int w = tid >> 6, l = tid & 63;
    const int lr = l & 15, lq = l >> 4;
    const int q0 = c * 64, kpos0 = q0 - 64, v0c = vt * 128;
    const size_t rowbase = (size_t)b * L_;

    __shared__ alignas(16) unsigned short Vt[128 * SV_];

    // ---- stage V transposed: Vt[vcol][key] ----
    {
        const int a = tid & 15;       // col group (8 cols)
        const int kr0 = tid >> 4;
        for (int kr = kr0; kr < 128; kr += 16) {
            int kp = kpos0 + kr;
            ushort4 u0 = {0, 0, 0, 0}, u1 = {0, 0, 0, 0};
            if (kp >= 0) {
                const unsigned short* src =
                    Abuf + (rowbase + kp) * K2_ + H_ + v0c + a * 8;
                u0 = *(const ushort4*)src;
                u1 = *(const ushort4*)(src + 4);
            }
            unsigned short vals[8] = {u0.x, u0.y, u0.z, u0.w,
                                      u1.x, u1.y, u1.z, u1.w};
            #pragma unroll
            for (int j = 0; j < 8; ++j)
                Vt[(a * 8 + j) * SV_ + kr] = vals[j];
        }
    }

    // P fragments from global (independent of the LDS staging)
    bf16x8 ap[4];
    {
        const unsigned short* prow =
            Pbuf + ((size_t)(b * 32 + c) * 64 + 16 * w + lr) * 128;
        #pragma unroll
        for (int kt = 0; kt < 4; ++kt)
            ap[kt] = *(const bf16x8*)(prow + kt * 32 + lq * 8);
    }
    __syncthreads();

    float rsum[4] = {0.f, 0.f, 0.f, 0.f};
    #pragma unroll
    for (int jt = 0; jt < 8; ++jt) {
        f32x4 oa = {};
        const int n = jt * 16 + lr;
        #pragma unroll
        for (int kt = 0; kt < 4; ++kt) {
            const unsigned int* vp =
                (const unsigned int*)(Vt + n * SV_ + kt * 32 + lq * 8);
            union { unsigned int u[4]; bf16x8 v; } bb;
            bb.u[0] = vp[0]; bb.u[1] = vp[1]; bb.u[2] = vp[2]; bb.u[3] = vp[3];
            oa = __builtin_amdgcn_mfma_f32_16x16x32_bf16(ap[kt], bb.v, oa, 0, 0, 0);
        }
        #pragma unroll
        for (int reg = 0; reg < 4; ++reg) {
            int qrow = 16 * w + lq * 4 + reg;
            size_t orow = rowbase + q0 + qrow;
            float val = oa[reg];
            Abuf[orow * K2_ + v0c + n] = f2bf(val);
            rsum[reg] += val * val;
        }
    }
    // reduce sum(o^2) over the 16 lanes sharing lq
    #pragma unroll
    for (int mk = 1; mk < 16; mk <<= 1) {
        #pragma unroll
        for (int reg = 0; reg < 4; ++reg)
            rsum[reg] += __shfl_xor(rsum[reg], mk, 64);
    }
    if (lr == 0) {
        #pragma unroll
        for (int reg = 0; reg < 4; ++reg)
            atomicAdd(&rrms_acc[rowbase + q0 + 16 * w + lq * 4 + reg], rsum[reg]);
    }
}

// ---------------------------------------------------------------------------
// Kernel 4: go = A @ B^T via bf16 MFMA — 8-phase-style pipelined schedule.
//   BM=256, BN=128, BK=64; grid 16x16 = 256 blocks (1/CU); 512 thr = 8 waves
//   (4M x 2N, 64x64 per wave, acc[4][4]).
//   3-deep LDS ring (144 KB), prefetch distance 2 K-tiles, counted
//   s_waitcnt vmcnt(6) once per K-tile (never drained to 0 in main loop),
//   raw s_barrier (no vmcnt drain), s_setprio(1) around MFMA clusters.
//   Per K-tile: 4 quadrant-phases of 8 MFMA; 16 ds_read_b128 with fragment
//   register reuse. Same XOR-swizzle scheme as before (measured 0 conflicts).
// Fused epilogue: rv = rsqrt(mean(o^2)+eps); out = (o*rv*gw)*go*sigmoid(go).
// M=4096, N=2048, K=4096. Accumulation order per element identical to the
// previous (verified) kernel.
// ---------------------------------------------------------------------------
__global__ __launch_bounds__(512, 2) void out_gemm_mfma(
    const unsigned short* __restrict__ Abuf,
    const unsigned short* __restrict__ Bbuf,
    const float* __restrict__ gw, const float* __restrict__ rrms_acc,
    float* __restrict__ out)
{
    __shared__ alignas(16) unsigned short As[3 * 256 * 64];   // 96 KB
    __shared__ alignas(16) unsigned short Bs[3 * 128 * 64];   // 48 KB
    const int tid  = threadIdx.x;
    const int w    = tid >> 6;      // 0..7
    const int lane = tid & 63;
    const int wr   = w >> 1;        // 0..3  (64-row slice)
    const int wc   = w & 1;         // 0..1  (64-col slice)
    const int m0 = blockIdx.x * 256;
    const int n0 = blockIdx.y * 128;

    const int frow = lane & 15;
    const int fkb  = (lane >> 4) << 3;       // 0,8,16,24
    const int rxor = (lane & 7) << 3;        // read-side XOR (row&7 == lane&7)

    // staging: thread tid covers rows it*64 + (tid>>3), 16B chunk (tid&7).
    // LDS dest is linear; source column pre-swizzled by (row&7).
    const int srow = tid >> 3;                              // 0..63
    const int scol = (((tid & 7) ^ (srow & 7)) << 3);
    const unsigned short* agsrc = Abuf + (size_t)(m0 + srow) * K2_ + scol;
    const unsigned short* bgsrc = Bbuf + (size_t)(n0 + srow) * K2_ + scol;
    unsigned short* As_dst = As + tid * 8;
    unsigned short* Bs_dst = Bs + tid * 8;

#define STAGE_A_(cb, k0)                                                     \
    {                                                                        \
        _Pragma("unroll")                                                    \
        for (int it_ = 0; it_ < 4; ++it_)                                    \
            ASYNC_COPY16(agsrc + (size_t)(it_ * 64) * K2_ + (k0),            \
                         As_dst + (cb) * 16384 + it_ * 4096);                \
    }
#define STAGE_B_(cb, k0)                                                     \
    {                                                                        \
        _Pragma("unroll")                                                    \
        for (int it_ = 0; it_ < 2; ++it_)                                    \
            ASYNC_COPY16(bgsrc + (size_t)(it_ * 64) * K2_ + (k0),            \
                         Bs_dst + (cb) * 8192 + it_ * 4096);                 \
    }
#define LDA_(buf, i_, ks_)                                                   \
    (*(const bf16x8*)((buf) + (wr * 64 + (i_) * 16 + frow) * 64 +            \
                      (((ks_) * 32 + fkb) ^ rxor)))
#define LDB_(buf, j_, ks_)                                                   \
    (*(const bf16x8*)((buf) + (wc * 64 + (j_) * 16 + frow) * 64 +            \
                      (((ks_) * 32 + fkb) ^ rxor)))
#define MFMA_(a_, b_, c_)                                                    \
    (c_) = __builtin_amdgcn_mfma_f32_16x16x32_bf16((a_), (b_), (c_), 0, 0, 0)

    f32x4 acc[4][4] = {};

    // ---- prologue: stage tiles 0 and 1; wait for tile 0 only ----
    STAGE_A_(0, 0); STAGE_B_(0, 0);
    STAGE_A_(1, 64); STAGE_B_(1, 64);
    asm volatile("s_waitcnt vmcnt(6)" ::: "memory");
    BAR();

    int cur = 0;
    for (int t = 0; t < 64; ++t) {
        const unsigned short* Ab = As + cur * 16384;
        const unsigned short* Bb = Bs + cur * 8192;
        int stg = cur + 2; if (stg >= 3) stg -= 3;
        const int kpre = (t + 2) * 64;
        const bool pre = (t + 2 < 64);
        bf16x8 af[2][2], bfr[4][2];

        // ---- phase 0: quadrant (i 0-1, j 0-1); issue A-prefetch(t+2) ----
        #pragma unroll
        for (int ii = 0; ii < 2; ++ii) {
            af[ii][0] = LDA_(Ab, ii, 0);
            af[ii][1] = LDA_(Ab, ii, 1);
        }
        #pragma unroll
        for (int j = 0; j < 2; ++j) {
            bfr[j][0] = LDB_(Bb, j, 0);
            bfr[j][1] = LDB_(Bb, j, 1);
        }
        if (pre) STAGE_A_(stg, kpre);
        BAR();
        __builtin_amdgcn_s_setprio(1);
        #pragma unroll
        for (int ii = 0; ii < 2; ++ii)
            #pragma unroll
            for (int j = 0; j < 2; ++j) {
                MFMA_(af[ii][0], bfr[j][0], acc[ii][j]);
                MFMA_(af[ii][1], bfr[j][1], acc[ii][j]);
            }
        __builtin_amdgcn_s_setprio(0);
        BAR();

        // ---- phase 1: quadrant (i 0-1, j 2-3); issue B-prefetch(t+2) ----
        #pragma unroll
        for (int j = 0; j < 2; ++j) {
            bfr[2 + j][0] = LDB_(Bb, 2 + j, 0);
            bfr[2 + j][1] = LDB_(Bb, 2 + j, 1);
        }
        if (pre) STAGE_B_(stg, kpre);
        BAR();
        __builtin_amdgcn_s_setprio(1);
        #pragma unroll
        for (int ii = 0; ii < 2; ++ii)
            #pragma unroll
            for (int j = 0; j < 2; ++j) {
                MFMA_(af[ii][0], bfr[2 + j][0], acc[ii][2 + j]);
                MFMA_(af[ii][1], bfr[2 + j][1], acc[ii][2 + j]);
            }
        __builtin_amdgcn_s_setprio(0);
        BAR();

        // ---- phase 2: quadrant (i 2-3, j 0-1); reuse bfr[0..1] ----
        #pragma unroll
        for (int ii = 0; ii < 2; ++ii) {
            af[ii][0] = LDA_(Ab, 2 + ii, 0);
            af[ii][1] = LDA_(Ab, 2 + ii, 1);
        }
        BAR();
        __builtin_amdgcn_s_setprio(1);
        #pragma unroll
        for (int ii = 0; ii < 2; ++ii)
            #pragma unroll
            for (int j = 0; j < 2; ++j) {
                MFMA_(af[ii][0], bfr[j][0], acc[2 + ii][j]);
                MFMA_(af[ii][1], bfr[j][1], acc[2 + ii][j]);
            }
        __builtin_amdgcn_s_setprio(0);
        BAR();

        // ---- phase 3: quadrant (i 2-3, j 2-3); counted-vmcnt checkpoint ----
        __builtin_amdgcn_s_setprio(1);
        #pragma unroll
        for (int ii = 0; ii < 2; ++ii)
            #pragma unroll
            for (int j = 0; j < 2; ++j) {
                MFMA_(af[ii][0], bfr[2 + j][0], acc[2 + ii][2 + j]);
                MFMA_(af[ii][1], bfr[2 + j][1], acc[2 + ii][2 + j]);
            }
        __builtin_amdgcn_s_setprio(0);
        // tile t+1 must be resident for next iter; tile t+2's 6 loads stay
        // in flight (never drain to 0 in steady state).
        if (pre) { asm volatile("s_waitcnt vmcnt(6)" ::: "memory"); }
        else     { asm volatile("s_waitcnt vmcnt(0)" ::: "memory"); }
        BAR();
        cur = cur + 1; if (cur == 3) cur = 0;
    }

#undef STAGE_A_
#undef STAGE_B_
#undef LDA_
#undef LDB_
#undef MFMA_

    // ---- fused epilogue (unchanged math) ----
    #pragma unroll
    for (int i = 0; i < 4; ++i) {
        #pragma unroll
        for (int reg = 0; reg < 4; ++reg) {
            int m = m0 + wr * 64 + i * 16 + (lane >> 4) * 4 + reg;
            float rv = rsqrtf(rrms_acc[m] * (1.0f / H_) + EPS_);
            #pragma unroll
            for (int j = 0; j < 4; ++j) {
                int n = n0 + wc * 64 + j * 16 + (lane & 15);
                float go = acc[i][j][reg];
                float ov = bf2f(Abuf[(size_t)m * K2_ + n]);   // bf16 o
                out[(size_t)m * H_ + n] = ov * rv * gw[n] * go * sigmoidf_(go);
            }
        }
    }
}

// ---------------------------------------------------------------------------
extern "C" void kernel_launch(void* const* d_in, const int* in_sizes, int n_in,
                              void* d_out, int out_size, void* d_ws, size_t ws_size,
                              hipStream_t stream) {
    (void)in_sizes; (void)n_in; (void)out_size; (void)ws_size;
    const float* x   = (const float*)d_in[0];
    const float* Wq  = (const float*)d_in[1];
    const float* Wk  = (const float*)d_in[2];
    const float* Wog = (const float*)d_in[3];
    const float* Wig = (const float*)d_in[4];
    const float* gw  = (const float*)d_in[5];
    float* out = (float*)d_out;

    const size_t MK = (size_t)B_ * L_ * KD_;               // 524288
    unsigned short* Abuf = (unsigned short*)d_ws;          // [4096][4096] bf16
    unsigned short* Bbuf = Abuf + (size_t)4096 * K2_;      // [2048][4096] bf16
    unsigned short* qt_b = Bbuf + (size_t)2048 * K2_;      // [4096][128] bf16
    unsigned short* kA_b = qt_b + MK;
    unsigned short* kB_b = kA_b + MK;
    unsigned short* Wqk  = kB_b + MK;                      // [256][2048] bf16
    unsigned short* Pbuf = Wqk + (size_t)256 * H_;         // [64][64][128] bf16
    float* partial  = (float*)(Pbuf + (size_t)64 * 64 * 128);  // [4][4096][256]
    float* rrms_acc = partial + (size_t)4 * 4096 * 256;    // [4096] fp32
    // ws use: 48 MB bf16 GEMM bufs + 3 MB qk + 1 MB W + 1 MB P + 16 MB partial

    prep_all<<<JOBA_BLKS + JOBB_BLKS + JOBC_BLKS, 256, 0, stream>>>(
        x, Wq, Wk, Wog, Wig, Abuf, Wqk, Bbuf, rrms_acc);
    qk_proj_mfma<<<dim3(32, 2, 4), 256, 0, stream>>>(Abuf, Wqk, partial);
    scan_scale_kernel<<<dim3(32, B_, 4), 256, 0, stream>>>(partial, qt_b, kA_b, kB_b);
    p_kernel<<<dim3(32, B_), 256, 0, stream>>>(qt_b, kA_b, kB_b, Pbuf);
    pv_kernel<<<dim3(32, B_, 16), 256, 0, stream>>>(Pbuf, Abuf, rrms_acc);
    out_gemm_mfma<<<dim3(16, 16), 512, 0, stream>>>(Abuf, Bbuf, gw, rrms_acc, out);
}

// Round 2
// 242.170 us; speedup vs baseline: 1.0944x; 1.0944x over previous
//
#include <hip/hip_runtime.h>
#include <math.h>

// Problem constants (B=2, L=2048, H=2048, K=H/NH=128)
#define B_ 2
#define L_ 2048
#define H_ 2048
#define KD_ 128
#define SCALE_ 0.08838834764831845f  // 128^-0.5
#define EPS_ 1e-5f
#define K2_ 4096                     // concat-K for the dual output GEMM

typedef __bf16 bf16x8 __attribute__((ext_vector_type(8)));
typedef float f32x4 __attribute__((ext_vector_type(4)));

static __device__ __forceinline__ float sigmoidf_(float z) {
    return 1.0f / (1.0f + __expf(-z));
}

static __device__ __forceinline__ unsigned short f2bf(float f) {
    unsigned int u = __float_as_uint(f);
    unsigned int r = (u + 0x7fffu + ((u >> 16) & 1u)) >> 16;
    return (unsigned short)r;
}

static __device__ __forceinline__ float bf2f(unsigned short s) {
    return __uint_as_float(((unsigned int)s) << 16);
}

// async global->LDS, 16B per lane; lds base must be wave-uniform
#define ASYNC_COPY16(gsrc, ldst)                                             \
    __builtin_amdgcn_global_load_lds(                                        \
        (const __attribute__((address_space(1))) unsigned int*)(gsrc),       \
        (__attribute__((address_space(3))) unsigned int*)(ldst), 16, 0, 0)

// raw barrier with compiler memory fence (no vmcnt drain, unlike __syncthreads)
#define BAR()                                                                \
    do {                                                                     \
        asm volatile("" ::: "memory");                                       \
        __builtin_amdgcn_s_barrier();                                        \
        asm volatile("" ::: "memory");                                       \
    } while (0)

// ---------------------------------------------------------------------------
// Kernel 0 (merged prep): jobA cast x->bf16 (Abuf x-half) | jobB cast
// [Wq|Wk]->bf16 + zero rrms_acc | jobC cast [Wog|Wig]->bf16 (Bbuf).
// ---------------------------------------------------------------------------
#define JOBA_BLKS 4096   // 1048576 groups of 8
#define JOBB_BLKS 256    // 65536 groups
#define JOBC_BLKS 4096   // 1048576 groups

__global__ __launch_bounds__(256) void prep_all(
    const float* __restrict__ x, const float* __restrict__ Wq,
    const float* __restrict__ Wk, const float* __restrict__ Wog,
    const float* __restrict__ Wig, unsigned short* __restrict__ Abuf,
    unsigned short* __restrict__ Wqk, unsigned short* __restrict__ Bbuf,
    float* __restrict__ rrms_acc)
{
    const int blk = blockIdx.x;
    const float* src;
    unsigned short* dst;
    if (blk < JOBA_BLKS) {
        size_t i = (size_t)blk * 256 + threadIdx.x;
        size_t m = i >> 8, c8 = (i & 255) * 8;
        src = x + m * H_ + c8;
        dst = Abuf + m * K2_ + H_ + c8;
    } else if (blk < JOBA_BLKS + JOBB_BLKS) {
        size_t i = (size_t)(blk - JOBA_BLKS) * 256 + threadIdx.x;
        if (i < 4096) rrms_acc[i] = 0.f;
        const size_t half = (size_t)KD_ * H_ / 8;   // 32768
        src = ((i < half) ? Wq : Wk) + ((i < half) ? i : i - half) * 8;
        dst = Wqk + i * 8;
    } else {
        size_t i = (size_t)(blk - JOBA_BLKS - JOBB_BLKS) * 256 + threadIdx.x;
        const size_t half = (size_t)H_ * H_ / 8;    // 524288
        size_t j = (i < half) ? i : i - half;
        size_t n = j >> 8, c8 = (j & 255) * 8;
        src = ((i < half) ? Wog : Wig) + n * H_ + c8;
        dst = Bbuf + n * K2_ + ((i < half) ? 0 : H_) + c8;
    }
    float4 v0 = *(const float4*)src;
    float4 v1 = *(const float4*)(src + 4);
    ushort4 a, b;
    a.x = f2bf(v0.x); a.y = f2bf(v0.y); a.z = f2bf(v0.z); a.w = f2bf(v0.w);
    b.x = f2bf(v1.x); b.y = f2bf(v1.y); b.z = f2bf(v1.z); b.w = f2bf(v1.w);
    *(ushort4*)dst = a;
    *(ushort4*)(dst + 4) = b;
}

// ---------------------------------------------------------------------------
// Kernel 1: qk projection GEMM via MFMA, split-K, XOR-swizzled LDS.
// A = x bf16 (Abuf x-half, row stride K2_), B = Wqk [256][2048] bf16.
// M=4096, N=256, K=2048 split into 4 slices of 512. Partials fp32 [4][4096][256].
// ---------------------------------------------------------------------------
__global__ __launch_bounds__(256) void qk_proj_mfma(
    const unsigned short* __restrict__ Abuf,
    const unsigned short* __restrict__ Wqk,
    float* __restrict__ partial)
{
    __shared__ alignas(16) unsigned short As[128 * 64];
    __shared__ alignas(16) unsigned short Bs[128 * 64];
    const int tid  = threadIdx.x;
    const int wave = tid >> 6;
    const int lane = tid & 63;
    const int m0 = blockIdx.x * 128;
    const int n0 = blockIdx.y * 128;
    const int kz = blockIdx.z * 512;
    const int wm = (wave >> 1) * 64;
    const int wn = (wave & 1) * 64;

    f32x4 acc[4][4] = {};

    const int se  = lane * 8;
    const int ldsbase = (wave * 4) * 512;
    const int frow = lane & 15;
    const int fk   = (lane >> 4) * 8;
    const int gswz = (((lane & 7) ^ (lane >> 3)) << 3);  // staging src column
    const int rswz = ((lane & 7) << 3);                  // fragment read XOR

    for (int k0 = kz; k0 < kz + 512; k0 += 64) {
        #pragma unroll
        for (int it = 0; it < 4; ++it) {
            int e = ldsbase + it * 512 + se;
            int r = e >> 6;
            const unsigned short* ga =
                Abuf + (size_t)(m0 + r) * K2_ + H_ + k0 + gswz;
            ASYNC_COPY16(ga, &As[e]);
            const unsigned short* gb = Wqk + (size_t)(n0 + r) * H_ + k0 + gswz;
            ASYNC_COPY16(gb, &Bs[e]);
        }
        __syncthreads();
        #pragma unroll
        for (int ksub = 0; ksub < 2; ++ksub) {
            bf16x8 af[4], bf[4];
            #pragma unroll
            for (int i = 0; i < 4; ++i)
                af[i] = *(const bf16x8*)(As + (wm + i * 16 + frow) * 64 +
                                         ((ksub * 32 + fk) ^ rswz));
            #pragma unroll
            for (int j = 0; j < 4; ++j)
                bf[j] = *(const bf16x8*)(Bs + (wn + j * 16 + frow) * 64 +
                                         ((ksub * 32 + fk) ^ rswz));
            #pragma unroll
            for (int i = 0; i < 4; ++i)
                #pragma unroll
                for (int j = 0; j < 4; ++j)
                    acc[i][j] = __builtin_amdgcn_mfma_f32_16x16x32_bf16(
                        af[i], bf[j], acc[i][j], 0, 0, 0);
        }
        __syncthreads();
    }

    float* pz = partial + (size_t)blockIdx.z * 4096 * 256;
    #pragma unroll
    for (int i = 0; i < 4; ++i) {
        #pragma unroll
        for (int reg = 0; reg < 4; ++reg) {
            int m = m0 + wm + i * 16 + (lane >> 4) * 4 + reg;
            #pragma unroll
            for (int j = 0; j < 4; ++j) {
                int n = n0 + wn + j * 16 + (lane & 15);
                pz[(size_t)m * 256 + n] = acc[i][j][reg];
            }
        }
    }
}

// ---------------------------------------------------------------------------
// Kernel 2 (fused): split-K reduce + epilogue + chunk-local gate scan +
// chunk-referenced bf16 scaling.
// ---------------------------------------------------------------------------
__global__ __launch_bounds__(256) void scan_scale_kernel(
    const float* __restrict__ partial,
    unsigned short* __restrict__ qt_b, unsigned short* __restrict__ kA_b,
    unsigned short* __restrict__ kB_b)
{
    const int c = blockIdx.x, b = blockIdx.y;
    const int kd = blockIdx.z * 32 + (threadIdx.x & 31);
    const int rg = threadIdx.x >> 5;              // 0..7
    const size_t stride = (size_t)4096 * 256;
    const int row0 = b * L_ + c * 64 + rg * 8;

    float qv[8], kv[8], gp[8];
    float run = 0.f;
    #pragma unroll
    for (int j = 0; j < 8; ++j) {
        size_t off = (size_t)(row0 + j) * 256;
        float sq = partial[off + kd] + partial[stride + off + kd]
                 + partial[2 * stride + off + kd] + partial[3 * stride + off + kd];
        float sk = partial[off + 128 + kd] + partial[stride + off + 128 + kd]
                 + partial[2 * stride + off + 128 + kd]
                 + partial[3 * stride + off + 128 + kd];
        float ksv = sigmoidf_(sk);
        qv[j] = sq * sigmoidf_(sq) * SCALE_;
        kv[j] = ksv;
        run += -log1pf(__expf(ksv));   // g_t in (-1.3133, -0.6931)
        gp[j] = run;
    }
    __shared__ float s_seg[8][32];
    s_seg[rg][threadIdx.x & 31] = run;
    __syncthreads();
    float base = 0.f, total = 0.f;
    #pragma unroll
    for (int r = 0; r < 8; ++r) {
        float v = s_seg[r][threadIdx.x & 31];
        base += (r < rg) ? v : 0.f;
        total += v;
    }
    #pragma unroll
    for (int j = 0; j < 8; ++j) {
        float s = base + gp[j];        // in [-84.05, -0.69]: exp in fp32 range
        size_t idx = (size_t)(row0 + j) * KD_ + kd;
        qt_b[idx] = f2bf(qv[j] * __expf(s));
        kA_b[idx] = f2bf(kv[j] * __expf(-s));
        kB_b[idx] = f2bf(kv[j] * __expf(total - s));
    }
}

// ---------------------------------------------------------------------------
// Kernel 3a: P = qt . k~^T, computed ONCE per (chunk, batch) with causal-band
// mask; written bf16 to Pbuf[cb][64 q][128 keys].
// ---------------------------------------------------------------------------
__global__ __launch_bounds__(256) void p_kernel(
    const unsigned short* __restrict__ qt_b,
    const unsigned short* __restrict__ kA_b,
    const unsigned short* __restrict__ kB_b,
    unsigned short* __restrict__ Pbuf)
{
    const int c = blockIdx.x, b = blockIdx.y;
    const int tid = threadIdx.x;
    const int w = tid >> 6, l = tid & 63;
    const int lr = l & 15, lq = l >> 4;
    const int q0 = c * 64;
    const size_t rowbase = (size_t)b * L_;

    bf16x8 aq[4];
    {
        const unsigned short* qrow = qt_b + (rowbase + q0 + 16 * w + lr) * KD_;
        #pragma unroll
        for (int kt = 0; kt < 4; ++kt)
            aq[kt] = *(const bf16x8*)(qrow + kt * 32 + lq * 8);
    }
    unsigned short* pout = Pbuf + (size_t)(b * 32 + c) * 64 * 128;
    #pragma unroll
    for (int jt = 0; jt < 8; ++jt) {
        f32x4 p = {};
        const int si = jt * 16 + lr;          // window key index 0..127
        const bool prev = (jt < 4);
        const bool dead = (c == 0 && prev);
        if (!dead) {
            int kp = prev ? (q0 - 64 + si) : (q0 + si - 64);
            const unsigned short* kb = (prev ? kB_b : kA_b) + (rowbase + kp) * KD_;
            #pragma unroll
            for (int kt = 0; kt < 4; ++kt) {
                bf16x8 bk = *(const bf16x8*)(kb + kt * 32 + lq * 8);
                p = __builtin_amdgcn_mfma_f32_16x16x32_bf16(aq[kt], bk, p, 0, 0, 0);
            }
        }
        #pragma unroll
        for (int reg = 0; reg < 4; ++reg) {
            int ti = 16 * w + lq * 4 + reg;   // q row 0..63
            bool keep = !dead && (si <= ti + 64);
            pout[ti * 128 + si] = keep ? f2bf(p[reg]) : (unsigned short)0;
        }
    }
}

// ---------------------------------------------------------------------------
// Kernel 3b: O = P @ V. Stages V transposed in LDS; P read from global
// (L2-hot, 1 MB). Writes bf16 o into Abuf o-half + rrms atomics.
// ---------------------------------------------------------------------------
#define SV_ 130   // Vt row stride (elems)

__global__ __launch_bounds__(256) void pv_kernel(
    const unsigned short* __restrict__ Pbuf,
    unsigned short* Abuf,          // reads x-half (cols 2048+), writes o-half
    float* __restrict__ rrms_acc)
{
    const int c  = blockIdx.x;   // chunk 0..31
    const int b  = blockIdx.y;
    const int vt = blockIdx.z;   // 0..15
    const int tid = threadIdx.x;
    const int w = tid >> 6, l = tid & 63;
    const int lr = l & 15, lq = l >> 4;
    const int q0 = c * 64, kpos0 = q0 - 64, v0c = vt * 128;
    const size_t rowbase = (size_t)b * L_;

    __shared__ alignas(16) unsigned short Vt[128 * SV_];

    // ---- stage V transposed: Vt[vcol][key] ----
    {
        const int a = tid & 15;       // col group (8 cols)
        const int kr0 = tid >> 4;
        for (int kr = kr0; kr < 128; kr += 16) {
            int kp = kpos0 + kr;
            ushort4 u0 = {0, 0, 0, 0}, u1 = {0, 0, 0, 0};
            if (kp >= 0) {
                const unsigned short* src =
                    Abuf + (rowbase + kp) * K2_ + H_ + v0c + a * 8;
                u0 = *(const ushort4*)src;
                u1 = *(const ushort4*)(src + 4);
            }
            unsigned short vals[8] = {u0.x, u0.y, u0.z, u0.w,
                                      u1.x, u1.y, u1.z, u1.w};
            #pragma unroll
            for (int j = 0; j < 8; ++j)
                Vt[(a * 8 + j) * SV_ + kr] = vals[j];
        }
    }

    // P fragments from global (independent of the LDS staging)
    bf16x8 ap[4];
    {
        const unsigned short* prow =
            Pbuf + ((size_t)(b * 32 + c) * 64 + 16 * w + lr) * 128;
        #pragma unroll
        for (int kt = 0; kt < 4; ++kt)
            ap[kt] = *(const bf16x8*)(prow + kt * 32 + lq * 8);
    }
    __syncthreads();

    float rsum[4] = {0.f, 0.f, 0.f, 0.f};
    #pragma unroll
    for (int jt = 0; jt < 8; ++jt) {
        f32x4 oa = {};
        const int n = jt * 16 + lr;
        #pragma unroll
        for (int kt = 0; kt < 4; ++kt) {
            const unsigned int* vp =
                (const unsigned int*)(Vt + n * SV_ + kt * 32 + lq * 8);
            union { unsigned int u[4]; bf16x8 v; } bb;
            bb.u[0] = vp[0]; bb.u[1] = vp[1]; bb.u[2] = vp[2]; bb.u[3] = vp[3];
            oa = __builtin_amdgcn_mfma_f32_16x16x32_bf16(ap[kt], bb.v, oa, 0, 0, 0);
        }
        #pragma unroll
        for (int reg = 0; reg < 4; ++reg) {
            int qrow = 16 * w + lq * 4 + reg;
            size_t orow = rowbase + q0 + qrow;
            float val = oa[reg];
            Abuf[orow * K2_ + v0c + n] = f2bf(val);
            rsum[reg] += val * val;
        }
    }
    // reduce sum(o^2) over the 16 lanes sharing lq
    #pragma unroll
    for (int mk = 1; mk < 16; mk <<= 1) {
        #pragma unroll
        for (int reg = 0; reg < 4; ++reg)
            rsum[reg] += __shfl_xor(rsum[reg], mk, 64);
    }
    if (lr == 0) {
        #pragma unroll
        for (int reg = 0; reg < 4; ++reg)
            atomicAdd(&rrms_acc[rowbase + q0 + 16 * w + lq * 4 + reg], rsum[reg]);
    }
}

// ---------------------------------------------------------------------------
// Kernel 4: go = A @ B^T via bf16 MFMA — m201-geometry pipelined schedule.
//   BM=128, BN=256, BK=64; 1D grid of 256 blocks (1/CU, full fill, no
//   split-K). n0 = (bid&7)*256 pins each B-panel (2 MB) to one XCD's L2.
//   512 thr = 8 waves as 2M x 4N (64x64/wave, acc[4][4]).
//   Per K-tile: 2 phases x 16-MFMA clusters (m201 cluster size), 4 barriers
//   per iter (R0 had 8 around 8-MFMA clusters -> sync-dominated, 25% util).
//   3-deep LDS ring (144 KB), prefetch distance 2, ONE counted
//   s_waitcnt vmcnt(6) per iter (6 = next-next tile's loads stay in flight).
// Fused epilogue: rv = rsqrt(mean(o^2)+eps); out = (o*rv*gw)*go*sigmoid(go).
// M=4096, N=2048, K=4096. Per-element accumulation order identical to the
// verified R0/baseline kernels (k-step 0 then 1 per K-tile, ascending t).
// ---------------------------------------------------------------------------
__global__ __launch_bounds__(512, 2) void out_gemm_mfma(
    const unsigned short* __restrict__ Abuf,
    const unsigned short* __restrict__ Bbuf,
    const float* __restrict__ gw, const float* __restrict__ rrms_acc,
    float* __restrict__ out)
{
    __shared__ alignas(16) unsigned short As[3 * 128 * 64];   // 48 KB
    __shared__ alignas(16) unsigned short Bs[3 * 256 * 64];   // 96 KB
    const int tid  = threadIdx.x;
    const int lane = tid & 63;
    const int w    = tid >> 6;      // 0..7
    const int wrow = w >> 2;        // 0..1  (64-row slice of BM=128)
    const int wcol = w & 3;         // 0..3  (64-col slice of BN=256)
    const int bid  = blockIdx.x;
    const int m0 = (bid >> 3) * 128;   // 32 m-tiles
    const int n0 = (bid & 7) * 256;    // 8 n-tiles == 8 XCDs (T1 locality)

    const int frow = lane & 15;
    const int fkb  = (lane >> 4) << 3;       // 0,8,16,24
    const int rxor = (lane & 7) << 3;        // read-side XOR (row&7 == lane&7)

    // staging: thread tid covers row chunk (tid>>3) within a 64-row group,
    // 16B chunk (tid&7). LDS dest linear; source column pre-swizzled (row&7).
    const int srow = tid >> 3;                              // 0..63
    const int scol = (((tid & 7) ^ (srow & 7)) << 3);
    const unsigned short* agsrc = Abuf + (size_t)(m0 + srow) * K2_ + scol;
    const unsigned short* bgsrc = Bbuf + (size_t)(n0 + srow) * K2_ + scol;
    unsigned short* As_dst = As + tid * 8;
    unsigned short* Bs_dst = Bs + tid * 8;

// A tile = 128x64 = 8192 elems (2 row-groups); B tile = 256x64 = 16384 (4).
#define STAGE_A2_(cb, k0)                                                    \
    {                                                                        \
        ASYNC_COPY16(agsrc + (k0), As_dst + (cb) * 8192);                    \
        ASYNC_COPY16(agsrc + (size_t)64 * K2_ + (k0),                        \
                     As_dst + (cb) * 8192 + 4096);                           \
    }
#define STAGE_B1_(cb, k0, it_)                                               \
    ASYNC_COPY16(bgsrc + (size_t)((it_) * 64) * K2_ + (k0),                  \
                 Bs_dst + (cb) * 16384 + (it_) * 4096)
#define LDA_(buf, i_, ks_)                                                   \
    (*(const bf16x8*)(As + (buf) * 8192 +                                    \
                      (wrow * 64 + (i_) * 16 + frow) * 64 +                  \
                      (((ks_) * 32 + fkb) ^ rxor)))
#define LDB_(buf, j_, ks_)                                                   \
    (*(const bf16x8*)(Bs + (buf) * 16384 +                                   \
                      (wcol * 64 + (j_) * 16 + frow) * 64 +                  \
                      (((ks_) * 32 + fkb) ^ rxor)))
#define MFMA_(a_, b_, c_)                                                    \
    (c_) = __builtin_amdgcn_mfma_f32_16x16x32_bf16((a_), (b_), (c_), 0, 0, 0)

    f32x4 acc[4][4] = {};

    // ---- prologue: stage tiles 0 and 1 (6 loads each); wait tile 0 ----
    STAGE_A2_(0, 0);
    STAGE_B1_(0, 0, 0); STAGE_B1_(0, 0, 1); STAGE_B1_(0, 0, 2); STAGE_B1_(0, 0, 3);
    STAGE_A2_(1, 64);
    STAGE_B1_(1, 64, 0); STAGE_B1_(1, 64, 1); STAGE_B1_(1, 64, 2); STAGE_B1_(1, 64, 3);
    asm volatile("s_waitcnt vmcnt(6)" ::: "memory");
    BAR();

    int cur = 0;
    for (int t = 0; t < 64; ++t) {
        int stg = cur + 2; if (stg >= 3) stg -= 3;
        const int kpre = (t + 2) * 64;
        const bool pre = (t + 2 < 64);
        bf16x8 af[4], bfr[4];

        // ---- phase 0: k-step 0 (16 MFMA); stage A(2) + B0 of tile t+2 ----
        #pragma unroll
        for (int i = 0; i < 4; ++i) af[i] = LDA_(cur, i, 0);
        #pragma unroll
        for (int j = 0; j < 4; ++j) bfr[j] = LDB_(cur, j, 0);
        if (pre) {
            STAGE_A2_(stg, kpre);
            STAGE_B1_(stg, kpre, 0);
        }
        BAR();
        __builtin_amdgcn_s_setprio(1);
        #pragma unroll
        for (int i = 0; i < 4; ++i)
            #pragma unroll
            for (int j = 0; j < 4; ++j)
                MFMA_(af[i], bfr[j], acc[i][j]);
        __builtin_amdgcn_s_setprio(0);
        BAR();

        // ---- phase 1: k-step 1 (16 MFMA); stage B1-3 of tile t+2 ----
        #pragma unroll
        for (int i = 0; i < 4; ++i) af[i] = LDA_(cur, i, 1);
        #pragma unroll
        for (int j = 0; j < 4; ++j) bfr[j] = LDB_(cur, j, 1);
        if (pre) {
            STAGE_B1_(stg, kpre, 1);
            STAGE_B1_(stg, kpre, 2);
            STAGE_B1_(stg, kpre, 3);
        }
        // tile t+1 must be resident for next iter; tile t+2's 6 loads stay
        // in flight (never drain to 0 in steady state).
        if (pre) { asm volatile("s_waitcnt vmcnt(6)" ::: "memory"); }
        else     { asm volatile("s_waitcnt vmcnt(0)" ::: "memory"); }
        BAR();
        __builtin_amdgcn_s_setprio(1);
        #pragma unroll
        for (int i = 0; i < 4; ++i)
            #pragma unroll
            for (int j = 0; j < 4; ++j)
                MFMA_(af[i], bfr[j], acc[i][j]);
        __builtin_amdgcn_s_setprio(0);
        BAR();

        cur = cur + 1; if (cur == 3) cur = 0;
    }

#undef STAGE_A2_
#undef STAGE_B1_
#undef LDA_
#undef LDB_
#undef MFMA_

    // ---- fused epilogue (unchanged math) ----
    #pragma unroll
    for (int i = 0; i < 4; ++i) {
        #pragma unroll
        for (int reg = 0; reg < 4; ++reg) {
            int m = m0 + wrow * 64 + i * 16 + (lane >> 4) * 4 + reg;
            float rv = rsqrtf(rrms_acc[m] * (1.0f / H_) + EPS_);
            #pragma unroll
            for (int j = 0; j < 4; ++j) {
                int n = n0 + wcol * 64 + j * 16 + (lane & 15);
                float go = acc[i][j][reg];
                float ov = bf2f(Abuf[(size_t)m * K2_ + n]);   // bf16 o
                out[(size_t)m * H_ + n] = ov * rv * gw[n] * go * sigmoidf_(go);
            }
        }
    }
}

// ---------------------------------------------------------------------------
extern "C" void kernel_launch(void* const* d_in, const int* in_sizes, int n_in,
                              void* d_out, int out_size, void* d_ws, size_t ws_size,
                              hipStream_t stream) {
    (void)in_sizes; (void)n_in; (void)out_size; (void)ws_size;
    const float* x   = (const float*)d_in[0];
    const float* Wq  = (const float*)d_in[1];
    const float* Wk  = (const float*)d_in[2];
    const float* Wog = (const float*)d_in[3];
    const float* Wig = (const float*)d_in[4];
    const float* gw  = (const float*)d_in[5];
    float* out = (float*)d_out;

    const size_t MK = (size_t)B_ * L_ * KD_;               // 524288
    unsigned short* Abuf = (unsigned short*)d_ws;          // [4096][4096] bf16
    unsigned short* Bbuf = Abuf + (size_t)4096 * K2_;      // [2048][4096] bf16
    unsigned short* qt_b = Bbuf + (size_t)2048 * K2_;      // [4096][128] bf16
    unsigned short* kA_b = qt_b + MK;
    unsigned short* kB_b = kA_b + MK;
    unsigned short* Wqk  = kB_b + MK;                      // [256][2048] bf16
    unsigned short* Pbuf = Wqk + (size_t)256 * H_;         // [64][64][128] bf16
    float* partial  = (float*)(Pbuf + (size_t)64 * 64 * 128);  // [4][4096][256]
    float* rrms_acc = partial + (size_t)4 * 4096 * 256;    // [4096] fp32
    // ws use: 48 MB bf16 GEMM bufs + 3 MB qk + 1 MB W + 1 MB P + 16 MB partial

    prep_all<<<JOBA_BLKS + JOBB_BLKS + JOBC_BLKS, 256, 0, stream>>>(
        x, Wq, Wk, Wog, Wig, Abuf, Wqk, Bbuf, rrms_acc);
    qk_proj_mfma<<<dim3(32, 2, 4), 256, 0, stream>>>(Abuf, Wqk, partial);
    scan_scale_kernel<<<dim3(32, B_, 4), 256, 0, stream>>>(partial, qt_b, kA_b, kB_b);
    p_kernel<<<dim3(32, B_), 256, 0, stream>>>(qt_b, kA_b, kB_b, Pbuf);
    pv_kernel<<<dim3(32, B_, 16), 256, 0, stream>>>(Pbuf, Abuf, rrms_acc);
    out_gemm_mfma<<<256, 512, 0, stream>>>(Abuf, Bbuf, gw, rrms_acc, out);
}

// Round 3
// 233.694 us; speedup vs baseline: 1.1341x; 1.0363x over previous
//
#include <hip/hip_runtime.h>
#include <math.h>

// Problem constants (B=2, L=2048, H=2048, K=H/NH=128)
#define B_ 2
#define L_ 2048
#define H_ 2048
#define KD_ 128
#define SCALE_ 0.08838834764831845f  // 128^-0.5
#define EPS_ 1e-5f
#define K2_ 4096                     // concat-K for the dual output GEMM

typedef __bf16 bf16x8 __attribute__((ext_vector_type(8)));
typedef float f32x4 __attribute__((ext_vector_type(4)));

static __device__ __forceinline__ float sigmoidf_(float z) {
    return 1.0f / (1.0f + __expf(-z));
}

static __device__ __forceinline__ unsigned short f2bf(float f) {
    unsigned int u = __float_as_uint(f);
    unsigned int r = (u + 0x7fffu + ((u >> 16) & 1u)) >> 16;
    return (unsigned short)r;
}

static __device__ __forceinline__ float bf2f(unsigned short s) {
    return __uint_as_float(((unsigned int)s) << 16);
}

// async global->LDS, 16B per lane; lds base must be wave-uniform
#define ASYNC_COPY16(gsrc, ldst)                                             \
    __builtin_amdgcn_global_load_lds(                                        \
        (const __attribute__((address_space(1))) unsigned int*)(gsrc),       \
        (__attribute__((address_space(3))) unsigned int*)(ldst), 16, 0, 0)

// raw barrier with compiler memory fence (no vmcnt drain, unlike __syncthreads)
#define BAR()                                                                \
    do {                                                                     \
        asm volatile("" ::: "memory");                                       \
        __builtin_amdgcn_s_barrier();                                        \
        asm volatile("" ::: "memory");                                       \
    } while (0)

// ---------------------------------------------------------------------------
// Kernel 0 (merged prep): jobA cast x->bf16 (Abuf x-half) | jobB cast
// [Wq|Wk]->bf16 + zero rrms_acc | jobC cast [Wog|Wig]->bf16 (Bbuf).
// ---------------------------------------------------------------------------
#define JOBA_BLKS 4096   // 1048576 groups of 8
#define JOBB_BLKS 256    // 65536 groups
#define JOBC_BLKS 4096   // 1048576 groups

__global__ __launch_bounds__(256) void prep_all(
    const float* __restrict__ x, const float* __restrict__ Wq,
    const float* __restrict__ Wk, const float* __restrict__ Wog,
    const float* __restrict__ Wig, unsigned short* __restrict__ Abuf,
    unsigned short* __restrict__ Wqk, unsigned short* __restrict__ Bbuf,
    float* __restrict__ rrms_acc)
{
    const int blk = blockIdx.x;
    const float* src;
    unsigned short* dst;
    if (blk < JOBA_BLKS) {
        size_t i = (size_t)blk * 256 + threadIdx.x;
        size_t m = i >> 8, c8 = (i & 255) * 8;
        src = x + m * H_ + c8;
        dst = Abuf + m * K2_ + H_ + c8;
    } else if (blk < JOBA_BLKS + JOBB_BLKS) {
        size_t i = (size_t)(blk - JOBA_BLKS) * 256 + threadIdx.x;
        if (i < 4096) rrms_acc[i] = 0.f;
        const size_t half = (size_t)KD_ * H_ / 8;   // 32768
        src = ((i < half) ? Wq : Wk) + ((i < half) ? i : i - half) * 8;
        dst = Wqk + i * 8;
    } else {
        size_t i = (size_t)(blk - JOBA_BLKS - JOBB_BLKS) * 256 + threadIdx.x;
        const size_t half = (size_t)H_ * H_ / 8;    // 524288
        size_t j = (i < half) ? i : i - half;
        size_t n = j >> 8, c8 = (j & 255) * 8;
        src = ((i < half) ? Wog : Wig) + n * H_ + c8;
        dst = Bbuf + n * K2_ + ((i < half) ? 0 : H_) + c8;
    }
    float4 v0 = *(const float4*)src;
    float4 v1 = *(const float4*)(src + 4);
    ushort4 a, b;
    a.x = f2bf(v0.x); a.y = f2bf(v0.y); a.z = f2bf(v0.z); a.w = f2bf(v0.w);
    b.x = f2bf(v1.x); b.y = f2bf(v1.y); b.z = f2bf(v1.z); b.w = f2bf(v1.w);
    *(ushort4*)dst = a;
    *(ushort4*)(dst + 4) = b;
}

// ---------------------------------------------------------------------------
// Kernel 1: qk projection GEMM via MFMA, split-K, XOR-swizzled LDS.
// A = x bf16 (Abuf x-half, row stride K2_), B = Wqk [256][2048] bf16.
// M=4096, N=256, K=2048 split into 4 slices of 512. Partials fp32 [4][4096][256].
// ---------------------------------------------------------------------------
__global__ __launch_bounds__(256) void qk_proj_mfma(
    const unsigned short* __restrict__ Abuf,
    const unsigned short* __restrict__ Wqk,
    float* __restrict__ partial)
{
    __shared__ alignas(16) unsigned short As[128 * 64];
    __shared__ alignas(16) unsigned short Bs[128 * 64];
    const int tid  = threadIdx.x;
    const int wave = tid >> 6;
    const int lane = tid & 63;
    const int m0 = blockIdx.x * 128;
    const int n0 = blockIdx.y * 128;
    const int kz = blockIdx.z * 512;
    const int wm = (wave >> 1) * 64;
    const int wn = (wave & 1) * 64;

    f32x4 acc[4][4] = {};

    const int se  = lane * 8;
    const int ldsbase = (wave * 4) * 512;
    const int frow = lane & 15;
    const int fk   = (lane >> 4) * 8;
    const int gswz = (((lane & 7) ^ (lane >> 3)) << 3);  // staging src column
    const int rswz = ((lane & 7) << 3);                  // fragment read XOR

    for (int k0 = kz; k0 < kz + 512; k0 += 64) {
        #pragma unroll
        for (int it = 0; it < 4; ++it) {
            int e = ldsbase + it * 512 + se;
            int r = e >> 6;
            const unsigned short* ga =
                Abuf + (size_t)(m0 + r) * K2_ + H_ + k0 + gswz;
            ASYNC_COPY16(ga, &As[e]);
            const unsigned short* gb = Wqk + (size_t)(n0 + r) * H_ + k0 + gswz;
            ASYNC_COPY16(gb, &Bs[e]);
        }
        __syncthreads();
        #pragma unroll
        for (int ksub = 0; ksub < 2; ++ksub) {
            bf16x8 af[4], bf[4];
            #pragma unroll
            for (int i = 0; i < 4; ++i)
                af[i] = *(const bf16x8*)(As + (wm + i * 16 + frow) * 64 +
                                         ((ksub * 32 + fk) ^ rswz));
            #pragma unroll
            for (int j = 0; j < 4; ++j)
                bf[j] = *(const bf16x8*)(Bs + (wn + j * 16 + frow) * 64 +
                                         ((ksub * 32 + fk) ^ rswz));
            #pragma unroll
            for (int i = 0; i < 4; ++i)
                #pragma unroll
                for (int j = 0; j < 4; ++j)
                    acc[i][j] = __builtin_amdgcn_mfma_f32_16x16x32_bf16(
                        af[i], bf[j], acc[i][j], 0, 0, 0);
        }
        __syncthreads();
    }

    float* pz = partial + (size_t)blockIdx.z * 4096 * 256;
    #pragma unroll
    for (int i = 0; i < 4; ++i) {
        #pragma unroll
        for (int reg = 0; reg < 4; ++reg) {
            int m = m0 + wm + i * 16 + (lane >> 4) * 4 + reg;
            #pragma unroll
            for (int j = 0; j < 4; ++j) {
                int n = n0 + wn + j * 16 + (lane & 15);
                pz[(size_t)m * 256 + n] = acc[i][j][reg];
            }
        }
    }
}

// ---------------------------------------------------------------------------
// Kernel 2 (fused): split-K reduce + epilogue + chunk-local gate scan +
// chunk-referenced bf16 scaling.
// ---------------------------------------------------------------------------
__global__ __launch_bounds__(256) void scan_scale_kernel(
    const float* __restrict__ partial,
    unsigned short* __restrict__ qt_b, unsigned short* __restrict__ kA_b,
    unsigned short* __restrict__ kB_b)
{
    const int c = blockIdx.x, b = blockIdx.y;
    const int kd = blockIdx.z * 32 + (threadIdx.x & 31);
    const int rg = threadIdx.x >> 5;              // 0..7
    const size_t stride = (size_t)4096 * 256;
    const int row0 = b * L_ + c * 64 + rg * 8;

    float qv[8], kv[8], gp[8];
    float run = 0.f;
    #pragma unroll
    for (int j = 0; j < 8; ++j) {
        size_t off = (size_t)(row0 + j) * 256;
        float sq = partial[off + kd] + partial[stride + off + kd]
                 + partial[2 * stride + off + kd] + partial[3 * stride + off + kd];
        float sk = partial[off + 128 + kd] + partial[stride + off + 128 + kd]
                 + partial[2 * stride + off + 128 + kd]
                 + partial[3 * stride + off + 128 + kd];
        float ksv = sigmoidf_(sk);
        qv[j] = sq * sigmoidf_(sq) * SCALE_;
        kv[j] = ksv;
        run += -log1pf(__expf(ksv));   // g_t in (-1.3133, -0.6931)
        gp[j] = run;
    }
    __shared__ float s_seg[8][32];
    s_seg[rg][threadIdx.x & 31] = run;
    __syncthreads();
    float base = 0.f, total = 0.f;
    #pragma unroll
    for (int r = 0; r < 8; ++r) {
        float v = s_seg[r][threadIdx.x & 31];
        base += (r < rg) ? v : 0.f;
        total += v;
    }
    #pragma unroll
    for (int j = 0; j < 8; ++j) {
        float s = base + gp[j];        // in [-84.05, -0.69]: exp in fp32 range
        size_t idx = (size_t)(row0 + j) * KD_ + kd;
        qt_b[idx] = f2bf(qv[j] * __expf(s));
        kA_b[idx] = f2bf(kv[j] * __expf(-s));
        kB_b[idx] = f2bf(kv[j] * __expf(total - s));
    }
}

// ---------------------------------------------------------------------------
// Kernel 3a: P = qt . k~^T, computed ONCE per (chunk, batch) with causal-band
// mask; written bf16 to Pbuf[cb][64 q][128 keys].
// ---------------------------------------------------------------------------
__global__ __launch_bounds__(256) void p_kernel(
    const unsigned short* __restrict__ qt_b,
    const unsigned short* __restrict__ kA_b,
    const unsigned short* __restrict__ kB_b,
    unsigned short* __restrict__ Pbuf)
{
    const int c = blockIdx.x, b = blockIdx.y;
    const int tid = threadIdx.x;
    const int w = tid >> 6, l = tid & 63;
    const int lr = l & 15, lq = l >> 4;
    const int q0 = c * 64;
    const size_t rowbase = (size_t)b * L_;

    bf16x8 aq[4];
    {
        const unsigned short* qrow = qt_b + (rowbase + q0 + 16 * w + lr) * KD_;
        #pragma unroll
        for (int kt = 0; kt < 4; ++kt)
            aq[kt] = *(const bf16x8*)(qrow + kt * 32 + lq * 8);
    }
    unsigned short* pout = Pbuf + (size_t)(b * 32 + c) * 64 * 128;
    #pragma unroll
    for (int jt = 0; jt < 8; ++jt) {
        f32x4 p = {};
        const int si = jt * 16 + lr;          // window key index 0..127
        const bool prev = (jt < 4);
        const bool dead = (c == 0 && prev);
        if (!dead) {
            int kp = prev ? (q0 - 64 + si) : (q0 + si - 64);
            const unsigned short* kb = (prev ? kB_b : kA_b) + (rowbase + kp) * KD_;
            #pragma unroll
            for (int kt = 0; kt < 4; ++kt) {
                bf16x8 bk = *(const bf16x8*)(kb + kt * 32 + lq * 8);
                p = __builtin_amdgcn_mfma_f32_16x16x32_bf16(aq[kt], bk, p, 0, 0, 0);
            }
        }
        #pragma unroll
        for (int reg = 0; reg < 4; ++reg) {
            int ti = 16 * w + lq * 4 + reg;   // q row 0..63
            bool keep = !dead && (si <= ti + 64);
            pout[ti * 128 + si] = keep ? f2bf(p[reg]) : (unsigned short)0;
        }
    }
}

// ---------------------------------------------------------------------------
// Kernel 3b: O = P @ V. Stages V transposed in LDS; P read from global
// (L2-hot, 1 MB). Writes bf16 o into Abuf o-half + rrms atomics.
// ---------------------------------------------------------------------------
#define SV_ 130   // Vt row stride (elems)

__global__ __launch_bounds__(256) void pv_kernel(
    const unsigned short* __restrict__ Pbuf,
    unsigned short* Abuf,          // reads x-half (cols 2048+), writes o-half
    float* __restrict__ rrms_acc)
{
    const int c  = blockIdx.x;   // chunk 0..31
    const int b  = blockIdx.y;
    const int vt = blockIdx.z;   // 0..15
    const int tid = threadIdx.x;
    const int w = tid >> 6, l = tid & 63;
    const int lr = l & 15, lq = l >> 4;
    const int q0 = c * 64, kpos0 = q0 - 64, v0c = vt * 128;
    const size_t rowbase = (size_t)b * L_;

    __shared__ alignas(16) unsigned short Vt[128 * SV_];

    // ---- stage V transposed: Vt[vcol][key] ----
    {
        const int a = tid & 15;       // col group (8 cols)
        const int kr0 = tid >> 4;
        for (int kr = kr0; kr < 128; kr += 16) {
            int kp = kpos0 + kr;
            ushort4 u0 = {0, 0, 0, 0}, u1 = {0, 0, 0, 0};
            if (kp >= 0) {
                const unsigned short* src =
                    Abuf + (rowbase + kp) * K2_ + H_ + v0c + a * 8;
                u0 = *(const ushort4*)src;
                u1 = *(const ushort4*)(src + 4);
            }
            unsigned short vals[8] = {u0.x, u0.y, u0.z, u0.w,
                                      u1.x, u1.y, u1.z, u1.w};
            #pragma unroll
            for (int j = 0; j < 8; ++j)
                Vt[(a * 8 + j) * SV_ + kr] = vals[j];
        }
    }

    // P fragments from global (independent of the LDS staging)
    bf16x8 ap[4];
    {
        const unsigned short* prow =
            Pbuf + ((size_t)(b * 32 + c) * 64 + 16 * w + lr) * 128;
        #pragma unroll
        for (int kt = 0; kt < 4; ++kt)
            ap[kt] = *(const bf16x8*)(prow + kt * 32 + lq * 8);
    }
    __syncthreads();

    float rsum[4] = {0.f, 0.f, 0.f, 0.f};
    #pragma unroll
    for (int jt = 0; jt < 8; ++jt) {
        f32x4 oa = {};
        const int n = jt * 16 + lr;
        #pragma unroll
        for (int kt = 0; kt < 4; ++kt) {
            const unsigned int* vp =
                (const unsigned int*)(Vt + n * SV_ + kt * 32 + lq * 8);
            union { unsigned int u[4]; bf16x8 v; } bb;
            bb.u[0] = vp[0]; bb.u[1] = vp[1]; bb.u[2] = vp[2]; bb.u[3] = vp[3];
            oa = __builtin_amdgcn_mfma_f32_16x16x32_bf16(ap[kt], bb.v, oa, 0, 0, 0);
        }
        #pragma unroll
        for (int reg = 0; reg < 4; ++reg) {
            int qrow = 16 * w + lq * 4 + reg;
            size_t orow = rowbase + q0 + qrow;
            float val = oa[reg];
            Abuf[orow * K2_ + v0c + n] = f2bf(val);
            rsum[reg] += val * val;
        }
    }
    // reduce sum(o^2) over the 16 lanes sharing lq
    #pragma unroll
    for (int mk = 1; mk < 16; mk <<= 1) {
        #pragma unroll
        for (int reg = 0; reg < 4; ++reg)
            rsum[reg] += __shfl_xor(rsum[reg], mk, 64);
    }
    if (lr == 0) {
        #pragma unroll
        for (int reg = 0; reg < 4; ++reg)
            atomicAdd(&rrms_acc[rowbase + q0 + 16 * w + lq * 4 + reg], rsum[reg]);
    }
}

// ---------------------------------------------------------------------------
// Kernel 4: go = A @ B^T via bf16 MFMA — one-barrier ring schedule.
//   BM=128, BN=256, BK=64; 1D grid of 256 blocks (1/CU, full fill).
//   512 thr = 8 waves as 2M x 4N (64x64/wave, acc[4][4]).
//   ONE s_barrier per K-tile (preceded by counted s_waitcnt vmcnt(6)):
//   waves skew freely within the iter, so LDS-read time of one wave
//   overlaps MFMA time of another (R2's 4-barrier lockstep made them ADD:
//   measured 32% MfmaUtil = 1241cyc MFMA / (1241+1536 LDS + ovh)).
//   Ring-slot safety with 1 barrier: staging at iter t targets slot cur+2
//   == cur-1 (mod 3), read during iter t-1; all t-1 reads complete before
//   their wave's barrier arrival (every ds_read is consumed by an MFMA
//   before the barrier), and the barrier orders them before t's staging.
//   vmcnt(6) at the barrier: only this iter's 6 loads may remain in
//   flight => tile t+1 fully resident when iter t+1 begins.
// Fused epilogue: rv = rsqrt(mean(o^2)+eps); out = (o*rv*gw)*go*sigmoid(go).
// M=4096, N=2048, K=4096. Per-element accumulation order identical to the
// verified R2 kernel (ks0 then ks1 per K-tile, ascending t).
// ---------------------------------------------------------------------------
__global__ __launch_bounds__(512, 2) void out_gemm_mfma(
    const unsigned short* __restrict__ Abuf,
    const unsigned short* __restrict__ Bbuf,
    const float* __restrict__ gw, const float* __restrict__ rrms_acc,
    float* __restrict__ out)
{
    __shared__ alignas(16) unsigned short As[3 * 128 * 64];   // 48 KB
    __shared__ alignas(16) unsigned short Bs[3 * 256 * 64];   // 96 KB
    const int tid  = threadIdx.x;
    const int lane = tid & 63;
    const int w    = tid >> 6;      // 0..7
    const int wrow = w >> 2;        // 0..1  (64-row slice of BM=128)
    const int wcol = w & 3;         // 0..3  (64-col slice of BN=256)
    const int bid  = blockIdx.x;
    const int m0 = (bid >> 3) * 128;   // 32 m-tiles
    const int n0 = (bid & 7) * 256;    // 8 n-tiles == 8 XCDs (T1 locality)

    const int frow = lane & 15;
    const int fkb  = (lane >> 4) << 3;       // 0,8,16,24
    const int rxor = (lane & 7) << 3;        // read-side XOR (row&7 == lane&7)

    // staging: thread tid covers row chunk (tid>>3) within a 64-row group,
    // 16B chunk (tid&7). LDS dest linear; source column pre-swizzled (row&7).
    const int srow = tid >> 3;                              // 0..63
    const int scol = (((tid & 7) ^ (srow & 7)) << 3);
    const unsigned short* agsrc = Abuf + (size_t)(m0 + srow) * K2_ + scol;
    const unsigned short* bgsrc = Bbuf + (size_t)(n0 + srow) * K2_ + scol;
    unsigned short* As_dst = As + tid * 8;
    unsigned short* Bs_dst = Bs + tid * 8;

// A tile = 128x64 = 8192 elems (2 row-groups); B tile = 256x64 = 16384 (4).
#define STAGE_A2_(cb, k0)                                                    \
    {                                                                        \
        ASYNC_COPY16(agsrc + (k0), As_dst + (cb) * 8192);                    \
        ASYNC_COPY16(agsrc + (size_t)64 * K2_ + (k0),                        \
                     As_dst + (cb) * 8192 + 4096);                           \
    }
#define STAGE_B1_(cb, k0, it_)                                               \
    ASYNC_COPY16(bgsrc + (size_t)((it_) * 64) * K2_ + (k0),                  \
                 Bs_dst + (cb) * 16384 + (it_) * 4096)
#define LDA_(buf, i_, ks_)                                                   \
    (*(const bf16x8*)(As + (buf) * 8192 +                                    \
                      (wrow * 64 + (i_) * 16 + frow) * 64 +                  \
                      (((ks_) * 32 + fkb) ^ rxor)))
#define LDB_(buf, j_, ks_)                                                   \
    (*(const bf16x8*)(Bs + (buf) * 16384 +                                   \
                      (wcol * 64 + (j_) * 16 + frow) * 64 +                  \
                      (((ks_) * 32 + fkb) ^ rxor)))
#define MFMA_(a_, b_, c_)                                                    \
    (c_) = __builtin_amdgcn_mfma_f32_16x16x32_bf16((a_), (b_), (c_), 0, 0, 0)

    f32x4 acc[4][4] = {};

    // ---- prologue: stage tiles 0 and 1 (6 loads each); wait tile 0 ----
    STAGE_A2_(0, 0);
    STAGE_B1_(0, 0, 0); STAGE_B1_(0, 0, 1); STAGE_B1_(0, 0, 2); STAGE_B1_(0, 0, 3);
    STAGE_A2_(1, 64);
    STAGE_B1_(1, 64, 0); STAGE_B1_(1, 64, 1); STAGE_B1_(1, 64, 2); STAGE_B1_(1, 64, 3);
    asm volatile("s_waitcnt vmcnt(6)" ::: "memory");
    BAR();

    int cur = 0;
    for (int t = 0; t < 64; ++t) {
        int stg = cur + 2; if (stg >= 3) stg -= 3;
        const int kpre = (t + 2) * 64;
        const bool pre = (t + 2 < 64);
        bf16x8 af0[4], bf0[4], af1[4], bf1[4];

        // issue all 16 ds_reads of tile `cur` up front; compiler interleaves
        // MFMAs with fine-grained lgkmcnt as operands arrive.
        #pragma unroll
        for (int i = 0; i < 4; ++i) af0[i] = LDA_(cur, i, 0);
        #pragma unroll
        for (int j = 0; j < 4; ++j) bf0[j] = LDB_(cur, j, 0);
        #pragma unroll
        for (int i = 0; i < 4; ++i) af1[i] = LDA_(cur, i, 1);
        #pragma unroll
        for (int j = 0; j < 4; ++j) bf1[j] = LDB_(cur, j, 1);

        // issue next-next tile's staging (slot cur+2 == cur-1, safe: its
        // readers all passed the previous barrier).
        if (pre) {
            STAGE_A2_(stg, kpre);
            STAGE_B1_(stg, kpre, 0);
            STAGE_B1_(stg, kpre, 1);
            STAGE_B1_(stg, kpre, 2);
            STAGE_B1_(stg, kpre, 3);
        }

        __builtin_amdgcn_s_setprio(1);
        #pragma unroll
        for (int i = 0; i < 4; ++i)
            #pragma unroll
            for (int j = 0; j < 4; ++j)
                MFMA_(af0[i], bf0[j], acc[i][j]);
        #pragma unroll
        for (int i = 0; i < 4; ++i)
            #pragma unroll
            for (int j = 0; j < 4; ++j)
                MFMA_(af1[i], bf1[j], acc[i][j]);
        __builtin_amdgcn_s_setprio(0);

        // single sync point per K-tile: tile t+1 resident after this
        // (only this iter's 6 loads may remain outstanding).
        if (pre) { asm volatile("s_waitcnt vmcnt(6)" ::: "memory"); }
        else     { asm volatile("s_waitcnt vmcnt(0)" ::: "memory"); }
        BAR();

        cur = cur + 1; if (cur == 3) cur = 0;
    }

#undef STAGE_A2_
#undef STAGE_B1_
#undef LDA_
#undef LDB_
#undef MFMA_

    // ---- fused epilogue (unchanged math) ----
    #pragma unroll
    for (int i = 0; i < 4; ++i) {
        #pragma unroll
        for (int reg = 0; reg < 4; ++reg) {
            int m = m0 + wrow * 64 + i * 16 + (lane >> 4) * 4 + reg;
            float rv = rsqrtf(rrms_acc[m] * (1.0f / H_) + EPS_);
            #pragma unroll
            for (int j = 0; j < 4; ++j) {
                int n = n0 + wcol * 64 + j * 16 + (lane & 15);
                float go = acc[i][j][reg];
                float ov = bf2f(Abuf[(size_t)m * K2_ + n]);   // bf16 o
                out[(size_t)m * H_ + n] = ov * rv * gw[n] * go * sigmoidf_(go);
            }
        }
    }
}

// ---------------------------------------------------------------------------
extern "C" void kernel_launch(void* const* d_in, const int* in_sizes, int n_in,
                              void* d_out, int out_size, void* d_ws, size_t ws_size,
                              hipStream_t stream) {
    (void)in_sizes; (void)n_in; (void)out_size; (void)ws_size;
    const float* x   = (const float*)d_in[0];
    const float* Wq  = (const float*)d_in[1];
    const float* Wk  = (const float*)d_in[2];
    const float* Wog = (const float*)d_in[3];
    const float* Wig = (const float*)d_in[4];
    const float* gw  = (const float*)d_in[5];
    float* out = (float*)d_out;

    const size_t MK = (size_t)B_ * L_ * KD_;               // 524288
    unsigned short* Abuf = (unsigned short*)d_ws;          // [4096][4096] bf16
    unsigned short* Bbuf = Abuf + (size_t)4096 * K2_;      // [2048][4096] bf16
    unsigned short* qt_b = Bbuf + (size_t)2048 * K2_;      // [4096][128] bf16
    unsigned short* kA_b = qt_b + MK;
    unsigned short* kB_b = kA_b + MK;
    unsigned short* Wqk  = kB_b + MK;                      // [256][2048] bf16
    unsigned short* Pbuf = Wqk + (size_t)256 * H_;         // [64][64][128] bf16
    float* partial  = (float*)(Pbuf + (size_t)64 * 64 * 128);  // [4][4096][256]
    float* rrms_acc = partial + (size_t)4 * 4096 * 256;    // [4096] fp32
    // ws use: 48 MB bf16 GEMM bufs + 3 MB qk + 1 MB W + 1 MB P + 16 MB partial

    prep_all<<<JOBA_BLKS + JOBB_BLKS + JOBC_BLKS, 256, 0, stream>>>(
        x, Wq, Wk, Wog, Wig, Abuf, Wqk, Bbuf, rrms_acc);
    qk_proj_mfma<<<dim3(32, 2, 4), 256, 0, stream>>>(Abuf, Wqk, partial);
    scan_scale_kernel<<<dim3(32, B_, 4), 256, 0, stream>>>(partial, qt_b, kA_b, kB_b);
    p_kernel<<<dim3(32, B_), 256, 0, stream>>>(qt_b, kA_b, kB_b, Pbuf);
    pv_kernel<<<dim3(32, B_, 16), 256, 0, stream>>>(Pbuf, Abuf, rrms_acc);
    out_gemm_mfma<<<256, 512, 0, stream>>>(Abuf, Bbuf, gw, rrms_acc, out);
}

// Round 4
// 231.224 us; speedup vs baseline: 1.1462x; 1.0107x over previous
//
#include <hip/hip_runtime.h>
#include <math.h>

// Problem constants (B=2, L=2048, H=2048, K=H/NH=128)
#define B_ 2
#define L_ 2048
#define H_ 2048
#define KD_ 128
#define SCALE_ 0.08838834764831845f  // 128^-0.5
#define EPS_ 1e-5f
#define K2_ 4096                     // concat-K for the dual output GEMM

typedef __bf16 bf16x8 __attribute__((ext_vector_type(8)));
typedef float f32x4 __attribute__((ext_vector_type(4)));

static __device__ __forceinline__ float sigmoidf_(float z) {
    return 1.0f / (1.0f + __expf(-z));
}

static __device__ __forceinline__ unsigned short f2bf(float f) {
    unsigned int u = __float_as_uint(f);
    unsigned int r = (u + 0x7fffu + ((u >> 16) & 1u)) >> 16;
    return (unsigned short)r;
}

static __device__ __forceinline__ float bf2f(unsigned short s) {
    return __uint_as_float(((unsigned int)s) << 16);
}

// async global->LDS, 16B per lane; lds base must be wave-uniform
#define ASYNC_COPY16(gsrc, ldst)                                             \
    __builtin_amdgcn_global_load_lds(                                        \
        (const __attribute__((address_space(1))) unsigned int*)(gsrc),       \
        (__attribute__((address_space(3))) unsigned int*)(ldst), 16, 0, 0)

// raw barrier with compiler memory fence (no vmcnt drain, unlike __syncthreads)
#define BAR()                                                                \
    do {                                                                     \
        asm volatile("" ::: "memory");                                       \
        __builtin_amdgcn_s_barrier();                                        \
        asm volatile("" ::: "memory");                                       \
    } while (0)

// ---------------------------------------------------------------------------
// Kernel 0 (merged prep): jobA cast x->bf16 (Abuf x-half) | jobB cast
// [Wq|Wk]->bf16 + zero rrms_acc | jobC cast [Wog|Wig]->bf16 (Bbuf).
// ---------------------------------------------------------------------------
#define JOBA_BLKS 4096   // 1048576 groups of 8
#define JOBB_BLKS 256    // 65536 groups
#define JOBC_BLKS 4096   // 1048576 groups

__global__ __launch_bounds__(256) void prep_all(
    const float* __restrict__ x, const float* __restrict__ Wq,
    const float* __restrict__ Wk, const float* __restrict__ Wog,
    const float* __restrict__ Wig, unsigned short* __restrict__ Abuf,
    unsigned short* __restrict__ Wqk, unsigned short* __restrict__ Bbuf,
    float* __restrict__ rrms_acc)
{
    const int blk = blockIdx.x;
    const float* src;
    unsigned short* dst;
    if (blk < JOBA_BLKS) {
        size_t i = (size_t)blk * 256 + threadIdx.x;
        size_t m = i >> 8, c8 = (i & 255) * 8;
        src = x + m * H_ + c8;
        dst = Abuf + m * K2_ + H_ + c8;
    } else if (blk < JOBA_BLKS + JOBB_BLKS) {
        size_t i = (size_t)(blk - JOBA_BLKS) * 256 + threadIdx.x;
        if (i < 4096) rrms_acc[i] = 0.f;
        const size_t half = (size_t)KD_ * H_ / 8;   // 32768
        src = ((i < half) ? Wq : Wk) + ((i < half) ? i : i - half) * 8;
        dst = Wqk + i * 8;
    } else {
        size_t i = (size_t)(blk - JOBA_BLKS - JOBB_BLKS) * 256 + threadIdx.x;
        const size_t half = (size_t)H_ * H_ / 8;    // 524288
        size_t j = (i < half) ? i : i - half;
        size_t n = j >> 8, c8 = (j & 255) * 8;
        src = ((i < half) ? Wog : Wig) + n * H_ + c8;
        dst = Bbuf + n * K2_ + ((i < half) ? 0 : H_) + c8;
    }
    float4 v0 = *(const float4*)src;
    float4 v1 = *(const float4*)(src + 4);
    ushort4 a, b;
    a.x = f2bf(v0.x); a.y = f2bf(v0.y); a.z = f2bf(v0.z); a.w = f2bf(v0.w);
    b.x = f2bf(v1.x); b.y = f2bf(v1.y); b.z = f2bf(v1.z); b.w = f2bf(v1.w);
    *(ushort4*)dst = a;
    *(ushort4*)(dst + 4) = b;
}

// ---------------------------------------------------------------------------
// Kernel 1: qk projection GEMM — ported to the R3-verified one-barrier ring.
//   BM=64, BN=256 (full N in one block), BK=64; grid = 64 m-tiles x 4
//   k-slices = 256 blocks (1/CU, full fill). 512 thr = 8 waves as 2M x 4N
//   (32x64 per wave, acc[2][4]). K-slice = 512 = 8 K-tiles.
//   3-deep LDS ring (24+96=120 KB), prefetch distance 2, one counted
//   s_waitcnt vmcnt(5) + s_barrier per K-tile (5 loads/tile: 1 A + 4 B).
//   K-partition and per-element MFMA accumulation sequence identical to the
//   old kernel (slice z covers [z*512,(z+1)*512), ksub 0 then 1 per tile,
//   ascending tiles) => bit-identical partial results.
// A = x bf16 (Abuf x-half, row stride K2_), B = Wqk [256][2048] bf16.
// Partials fp32 [4][4096][256].
// ---------------------------------------------------------------------------
__global__ __launch_bounds__(512, 2) void qk_proj_mfma(
    const unsigned short* __restrict__ Abuf,
    const unsigned short* __restrict__ Wqk,
    float* __restrict__ partial)
{
    __shared__ alignas(16) unsigned short As[3 * 64 * 64];    // 24 KB
    __shared__ alignas(16) unsigned short Bs[3 * 256 * 64];   // 96 KB
    const int tid  = threadIdx.x;
    const int lane = tid & 63;
    const int w    = tid >> 6;      // 0..7
    const int wrow = w >> 2;        // 0..1  (32-row slice of BM=64)
    const int wcol = w & 3;         // 0..3  (64-col slice of BN=256)
    const int bid  = blockIdx.x;
    const int m0 = (bid >> 2) * 64;    // 64 m-tiles
    const int kz = (bid & 3) * 512;    // 4 K-slices (same partition as before)

    const int frow = lane & 15;
    const int fkb  = (lane >> 4) << 3;       // 0,8,16,24
    const int rxor = (lane & 7) << 3;        // read-side XOR (row&7 == lane&7)

    const int srow = tid >> 3;                              // 0..63
    const int scol = (((tid & 7) ^ (srow & 7)) << 3);
    const unsigned short* agsrc =
        Abuf + (size_t)(m0 + srow) * K2_ + H_ + kz + scol;
    const unsigned short* bgsrc = Wqk + (size_t)srow * H_ + kz + scol;
    unsigned short* As_dst = As + tid * 8;
    unsigned short* Bs_dst = Bs + tid * 8;

// A tile = 64x64 = 4096 elems (1 load/thread); B tile = 256x64 = 16384 (4).
#define QSTAGE_A_(cb, k0)                                                    \
    ASYNC_COPY16(agsrc + (k0), As_dst + (cb) * 4096)
#define QSTAGE_B_(cb, k0, it_)                                               \
    ASYNC_COPY16(bgsrc + (size_t)((it_) * 64) * H_ + (k0),                   \
                 Bs_dst + (cb) * 16384 + (it_) * 4096)
#define QLDA_(buf, i_, ks_)                                                  \
    (*(const bf16x8*)(As + (buf) * 4096 +                                    \
                      (wrow * 32 + (i_) * 16 + frow) * 64 +                  \
                      (((ks_) * 32 + fkb) ^ rxor)))
#define QLDB_(buf, j_, ks_)                                                  \
    (*(const bf16x8*)(Bs + (buf) * 16384 +                                   \
                      (wcol * 64 + (j_) * 16 + frow) * 64 +                  \
                      (((ks_) * 32 + fkb) ^ rxor)))
#define MFMA_(a_, b_, c_)                                                    \
    (c_) = __builtin_amdgcn_mfma_f32_16x16x32_bf16((a_), (b_), (c_), 0, 0, 0)

    f32x4 acc[2][4] = {};

    // ---- prologue: stage tiles 0 and 1 (5 loads each); wait tile 0 ----
    QSTAGE_A_(0, 0);
    QSTAGE_B_(0, 0, 0); QSTAGE_B_(0, 0, 1); QSTAGE_B_(0, 0, 2); QSTAGE_B_(0, 0, 3);
    QSTAGE_A_(1, 64);
    QSTAGE_B_(1, 64, 0); QSTAGE_B_(1, 64, 1); QSTAGE_B_(1, 64, 2); QSTAGE_B_(1, 64, 3);
    asm volatile("s_waitcnt vmcnt(5)" ::: "memory");
    BAR();

    int cur = 0;
    for (int t = 0; t < 8; ++t) {
        int stg = cur + 2; if (stg >= 3) stg -= 3;
        const int kpre = (t + 2) * 64;
        const bool pre = (t + 2 < 8);
        bf16x8 af0[2], bf0[4], af1[2], bf1[4];

        #pragma unroll
        for (int i = 0; i < 2; ++i) af0[i] = QLDA_(cur, i, 0);
        #pragma unroll
        for (int j = 0; j < 4; ++j) bf0[j] = QLDB_(cur, j, 0);
        #pragma unroll
        for (int i = 0; i < 2; ++i) af1[i] = QLDA_(cur, i, 1);
        #pragma unroll
        for (int j = 0; j < 4; ++j) bf1[j] = QLDB_(cur, j, 1);

        if (pre) {
            QSTAGE_A_(stg, kpre);
            QSTAGE_B_(stg, kpre, 0);
            QSTAGE_B_(stg, kpre, 1);
            QSTAGE_B_(stg, kpre, 2);
            QSTAGE_B_(stg, kpre, 3);
        }

        __builtin_amdgcn_s_setprio(1);
        #pragma unroll
        for (int i = 0; i < 2; ++i)
            #pragma unroll
            for (int j = 0; j < 4; ++j)
                MFMA_(af0[i], bf0[j], acc[i][j]);
        #pragma unroll
        for (int i = 0; i < 2; ++i)
            #pragma unroll
            for (int j = 0; j < 4; ++j)
                MFMA_(af1[i], bf1[j], acc[i][j]);
        __builtin_amdgcn_s_setprio(0);

        if (pre) { asm volatile("s_waitcnt vmcnt(5)" ::: "memory"); }
        else     { asm volatile("s_waitcnt vmcnt(0)" ::: "memory"); }
        BAR();

        cur = cur + 1; if (cur == 3) cur = 0;
    }

#undef QSTAGE_A_
#undef QSTAGE_B_
#undef QLDA_
#undef QLDB_
#undef MFMA_

    float* pz = partial + (size_t)(bid & 3) * 4096 * 256;
    #pragma unroll
    for (int i = 0; i < 2; ++i) {
        #pragma unroll
        for (int reg = 0; reg < 4; ++reg) {
            int m = m0 + wrow * 32 + i * 16 + (lane >> 4) * 4 + reg;
            #pragma unroll
            for (int j = 0; j < 4; ++j) {
                int n = wcol * 64 + j * 16 + (lane & 15);
                pz[(size_t)m * 256 + n] = acc[i][j][reg];
            }
        }
    }
}

// ---------------------------------------------------------------------------
// Kernel 2 (fused): split-K reduce + epilogue + chunk-local gate scan +
// chunk-referenced bf16 scaling.
// ---------------------------------------------------------------------------
__global__ __launch_bounds__(256) void scan_scale_kernel(
    const float* __restrict__ partial,
    unsigned short* __restrict__ qt_b, unsigned short* __restrict__ kA_b,
    unsigned short* __restrict__ kB_b)
{
    const int c = blockIdx.x, b = blockIdx.y;
    const int kd = blockIdx.z * 32 + (threadIdx.x & 31);
    const int rg = threadIdx.x >> 5;              // 0..7
    const size_t stride = (size_t)4096 * 256;
    const int row0 = b * L_ + c * 64 + rg * 8;

    float qv[8], kv[8], gp[8];
    float run = 0.f;
    #pragma unroll
    for (int j = 0; j < 8; ++j) {
        size_t off = (size_t)(row0 + j) * 256;
        float sq = partial[off + kd] + partial[stride + off + kd]
                 + partial[2 * stride + off + kd] + partial[3 * stride + off + kd];
        float sk = partial[off + 128 + kd] + partial[stride + off + 128 + kd]
                 + partial[2 * stride + off + 128 + kd]
                 + partial[3 * stride + off + 128 + kd];
        float ksv = sigmoidf_(sk);
        qv[j] = sq * sigmoidf_(sq) * SCALE_;
        kv[j] = ksv;
        run += -log1pf(__expf(ksv));   // g_t in (-1.3133, -0.6931)
        gp[j] = run;
    }
    __shared__ float s_seg[8][32];
    s_seg[rg][threadIdx.x & 31] = run;
    __syncthreads();
    float base = 0.f, total = 0.f;
    #pragma unroll
    for (int r = 0; r < 8; ++r) {
        float v = s_seg[r][threadIdx.x & 31];
        base += (r < rg) ? v : 0.f;
        total += v;
    }
    #pragma unroll
    for (int j = 0; j < 8; ++j) {
        float s = base + gp[j];        // in [-84.05, -0.69]: exp in fp32 range
        size_t idx = (size_t)(row0 + j) * KD_ + kd;
        qt_b[idx] = f2bf(qv[j] * __expf(s));
        kA_b[idx] = f2bf(kv[j] * __expf(-s));
        kB_b[idx] = f2bf(kv[j] * __expf(total - s));
    }
}

// ---------------------------------------------------------------------------
// Kernel 3a: P = qt . k~^T, computed ONCE per (chunk, batch) with causal-band
// mask; written bf16 to Pbuf[cb][64 q][128 keys].
// ---------------------------------------------------------------------------
__global__ __launch_bounds__(256) void p_kernel(
    const unsigned short* __restrict__ qt_b,
    const unsigned short* __restrict__ kA_b,
    const unsigned short* __restrict__ kB_b,
    unsigned short* __restrict__ Pbuf)
{
    const int c = blockIdx.x, b = blockIdx.y;
    const int tid = threadIdx.x;
    const int w = tid >> 6, l = tid & 63;
    const int lr = l & 15, lq = l >> 4;
    const int q0 = c * 64;
    const size_t rowbase = (size_t)b * L_;

    bf16x8 aq[4];
    {
        const unsigned short* qrow = qt_b + (rowbase + q0 + 16 * w + lr) * KD_;
        #pragma unroll
        for (int kt = 0; kt < 4; ++kt)
            aq[kt] = *(const bf16x8*)(qrow + kt * 32 + lq * 8);
    }
    unsigned short* pout = Pbuf + (size_t)(b * 32 + c) * 64 * 128;
    #pragma unroll
    for (int jt = 0; jt < 8; ++jt) {
        f32x4 p = {};
        const int si = jt * 16 + lr;          // window key index 0..127
        const bool prev = (jt < 4);
        const bool dead = (c == 0 && prev);
        if (!dead) {
            int kp = prev ? (q0 - 64 + si) : (q0 + si - 64);
            const unsigned short* kb = (prev ? kB_b : kA_b) + (rowbase + kp) * KD_;
            #pragma unroll
            for (int kt = 0; kt < 4; ++kt) {
                bf16x8 bk = *(const bf16x8*)(kb + kt * 32 + lq * 8);
                p = __builtin_amdgcn_mfma_f32_16x16x32_bf16(aq[kt], bk, p, 0, 0, 0);
            }
        }
        #pragma unroll
        for (int reg = 0; reg < 4; ++reg) {
            int ti = 16 * w + lq * 4 + reg;   // q row 0..63
            bool keep = !dead && (si <= ti + 64);
            pout[ti * 128 + si] = keep ? f2bf(p[reg]) : (unsigned short)0;
        }
    }
}

// ---------------------------------------------------------------------------
// Kernel 3b: O = P @ V. Stages V transposed in LDS; P read from global
// (L2-hot, 1 MB). Writes bf16 o into Abuf o-half + rrms atomics.
// ---------------------------------------------------------------------------
#define SV_ 130   // Vt row stride (elems)

__global__ __launch_bounds__(256) void pv_kernel(
    const unsigned short* __restrict__ Pbuf,
    unsigned short* Abuf,          // reads x-half (cols 2048+), writes o-half
    float* __restrict__ rrms_acc)
{
    const int c  = blockIdx.x;   // chunk 0..31
    const int b  = blockIdx.y;
    const int vt = blockIdx.z;   // 0..15
    const int tid = threadIdx.x;
    const int w = tid >> 6, l = tid & 63;
    const int lr = l & 15, lq = l >> 4;
    const int q0 = c * 64, kpos0 = q0 - 64, v0c = vt * 128;
    const size_t rowbase = (size_t)b * L_;

    __shared__ alignas(16) unsigned short Vt[128 * SV_];

    // ---- stage V transposed: Vt[vcol][key] ----
    {
        const int a = tid & 15;       // col group (8 cols)
        const int kr0 = tid >> 4;
        for (int kr = kr0; kr < 128; kr += 16) {
            int kp = kpos0 + kr;
            ushort4 u0 = {0, 0, 0, 0}, u1 = {0, 0, 0, 0};
            if (kp >= 0) {
                const unsigned short* src =
                    Abuf + (rowbase + kp) * K2_ + H_ + v0c + a * 8;
                u0 = *(const ushort4*)src;
                u1 = *(const ushort4*)(src + 4);
            }
            unsigned short vals[8] = {u0.x, u0.y, u0.z, u0.w,
                                      u1.x, u1.y, u1.z, u1.w};
            #pragma unroll
            for (int j = 0; j < 8; ++j)
                Vt[(a * 8 + j) * SV_ + kr] = vals[j];
        }
    }

    // P fragments from global (independent of the LDS staging)
    bf16x8 ap[4];
    {
        const unsigned short* prow =
            Pbuf + ((size_t)(b * 32 + c) * 64 + 16 * w + lr) * 128;
        #pragma unroll
        for (int kt = 0; kt < 4; ++kt)
            ap[kt] = *(const bf16x8*)(prow + kt * 32 + lq * 8);
    }
    __syncthreads();

    float rsum[4] = {0.f, 0.f, 0.f, 0.f};
    #pragma unroll
    for (int jt = 0; jt < 8; ++jt) {
        f32x4 oa = {};
        const int n = jt * 16 + lr;
        #pragma unroll
        for (int kt = 0; kt < 4; ++kt) {
            const unsigned int* vp =
                (const unsigned int*)(Vt + n * SV_ + kt * 32 + lq * 8);
            union { unsigned int u[4]; bf16x8 v; } bb;
            bb.u[0] = vp[0]; bb.u[1] = vp[1]; bb.u[2] = vp[2]; bb.u[3] = vp[3];
            oa = __builtin_amdgcn_mfma_f32_16x16x32_bf16(ap[kt], bb.v, oa, 0, 0, 0);
        }
        #pragma unroll
        for (int reg = 0; reg < 4; ++reg) {
            int qrow = 16 * w + lq * 4 + reg;
            size_t orow = rowbase + q0 + qrow;
            float val = oa[reg];
            Abuf[orow * K2_ + v0c + n] = f2bf(val);
            rsum[reg] += val * val;
        }
    }
    // reduce sum(o^2) over the 16 lanes sharing lq
    #pragma unroll
    for (int mk = 1; mk < 16; mk <<= 1) {
        #pragma unroll
        for (int reg = 0; reg < 4; ++reg)
            rsum[reg] += __shfl_xor(rsum[reg], mk, 64);
    }
    if (lr == 0) {
        #pragma unroll
        for (int reg = 0; reg < 4; ++reg)
            atomicAdd(&rrms_acc[rowbase + q0 + 16 * w + lq * 4 + reg], rsum[reg]);
    }
}

// ---------------------------------------------------------------------------
// Kernel 4: go = A @ B^T via bf16 MFMA — one-barrier ring schedule (R3).
//   BM=128, BN=256, BK=64; 1D grid of 256 blocks (1/CU, full fill).
//   512 thr = 8 waves as 2M x 4N (64x64/wave, acc[4][4]). 3-deep LDS ring,
//   prefetch distance 2, one counted s_waitcnt vmcnt(6) + s_barrier per
//   K-tile. Measured R3: 76.5us, MfmaUtil 37%, bank conflicts 0.
// Fused epilogue: rv = rsqrt(mean(o^2)+eps); out = (o*rv*gw)*go*sigmoid(go).
// ---------------------------------------------------------------------------
__global__ __launch_bounds__(512, 2) void out_gemm_mfma(
    const unsigned short* __restrict__ Abuf,
    const unsigned short* __restrict__ Bbuf,
    const float* __restrict__ gw, const float* __restrict__ rrms_acc,
    float* __restrict__ out)
{
    __shared__ alignas(16) unsigned short As[3 * 128 * 64];   // 48 KB
    __shared__ alignas(16) unsigned short Bs[3 * 256 * 64];   // 96 KB
    const int tid  = threadIdx.x;
    const int lane = tid & 63;
    const int w    = tid >> 6;      // 0..7
    const int wrow = w >> 2;        // 0..1  (64-row slice of BM=128)
    const int wcol = w & 3;         // 0..3  (64-col slice of BN=256)
    const int bid  = blockIdx.x;
    const int m0 = (bid >> 3) * 128;   // 32 m-tiles
    const int n0 = (bid & 7) * 256;    // 8 n-tiles == 8 XCDs (T1 locality)

    const int frow = lane & 15;
    const int fkb  = (lane >> 4) << 3;       // 0,8,16,24
    const int rxor = (lane & 7) << 3;        // read-side XOR (row&7 == lane&7)

    const int srow = tid >> 3;                              // 0..63
    const int scol = (((tid & 7) ^ (srow & 7)) << 3);
    const unsigned short* agsrc = Abuf + (size_t)(m0 + srow) * K2_ + scol;
    const unsigned short* bgsrc = Bbuf + (size_t)(n0 + srow) * K2_ + scol;
    unsigned short* As_dst = As + tid * 8;
    unsigned short* Bs_dst = Bs + tid * 8;

// A tile = 128x64 = 8192 elems (2 row-groups); B tile = 256x64 = 16384 (4).
#define STAGE_A2_(cb, k0)                                                    \
    {                                                                        \
        ASYNC_COPY16(agsrc + (k0), As_dst + (cb) * 8192);                    \
        ASYNC_COPY16(agsrc + (size_t)64 * K2_ + (k0),                        \
                     As_dst + (cb) * 8192 + 4096);                           \
    }
#define STAGE_B1_(cb, k0, it_)                                               \
    ASYNC_COPY16(bgsrc + (size_t)((it_) * 64) * K2_ + (k0),                  \
                 Bs_dst + (cb) * 16384 + (it_) * 4096)
#define LDA_(buf, i_, ks_)                                                   \
    (*(const bf16x8*)(As + (buf) * 8192 +                                    \
                      (wrow * 64 + (i_) * 16 + frow) * 64 +                  \
                      (((ks_) * 32 + fkb) ^ rxor)))
#define LDB_(buf, j_, ks_)                                                   \
    (*(const bf16x8*)(Bs + (buf) * 16384 +                                   \
                      (wcol * 64 + (j_) * 16 + frow) * 64 +                  \
                      (((ks_) * 32 + fkb) ^ rxor)))
#define MFMA_(a_, b_, c_)                                                    \
    (c_) = __builtin_amdgcn_mfma_f32_16x16x32_bf16((a_), (b_), (c_), 0, 0, 0)

    f32x4 acc[4][4] = {};

    // ---- prologue: stage tiles 0 and 1 (6 loads each); wait tile 0 ----
    STAGE_A2_(0, 0);
    STAGE_B1_(0, 0, 0); STAGE_B1_(0, 0, 1); STAGE_B1_(0, 0, 2); STAGE_B1_(0, 0, 3);
    STAGE_A2_(1, 64);
    STAGE_B1_(1, 64, 0); STAGE_B1_(1, 64, 1); STAGE_B1_(1, 64, 2); STAGE_B1_(1, 64, 3);
    asm volatile("s_waitcnt vmcnt(6)" ::: "memory");
    BAR();

    int cur = 0;
    for (int t = 0; t < 64; ++t) {
        int stg = cur + 2; if (stg >= 3) stg -= 3;
        const int kpre = (t + 2) * 64;
        const bool pre = (t + 2 < 64);
        bf16x8 af0[4], bf0[4], af1[4], bf1[4];

        // issue all 16 ds_reads of tile `cur` up front; compiler interleaves
        // MFMAs with fine-grained lgkmcnt as operands arrive.
        #pragma unroll
        for (int i = 0; i < 4; ++i) af0[i] = LDA_(cur, i, 0);
        #pragma unroll
        for (int j = 0; j < 4; ++j) bf0[j] = LDB_(cur, j, 0);
        #pragma unroll
        for (int i = 0; i < 4; ++i) af1[i] = LDA_(cur, i, 1);
        #pragma unroll
        for (int j = 0; j < 4; ++j) bf1[j] = LDB_(cur, j, 1);

        // issue next-next tile's staging (slot cur+2 == cur-1, safe: its
        // readers all passed the previous barrier).
        if (pre) {
            STAGE_A2_(stg, kpre);
            STAGE_B1_(stg, kpre, 0);
            STAGE_B1_(stg, kpre, 1);
            STAGE_B1_(stg, kpre, 2);
            STAGE_B1_(stg, kpre, 3);
        }

        __builtin_amdgcn_s_setprio(1);
        #pragma unroll
        for (int i = 0; i < 4; ++i)
            #pragma unroll
            for (int j = 0; j < 4; ++j)
                MFMA_(af0[i], bf0[j], acc[i][j]);
        #pragma unroll
        for (int i = 0; i < 4; ++i)
            #pragma unroll
            for (int j = 0; j < 4; ++j)
                MFMA_(af1[i], bf1[j], acc[i][j]);
        __builtin_amdgcn_s_setprio(0);

        // single sync point per K-tile: tile t+1 resident after this
        // (only this iter's 6 loads may remain outstanding).
        if (pre) { asm volatile("s_waitcnt vmcnt(6)" ::: "memory"); }
        else     { asm volatile("s_waitcnt vmcnt(0)" ::: "memory"); }
        BAR();

        cur = cur + 1; if (cur == 3) cur = 0;
    }

#undef STAGE_A2_
#undef STAGE_B1_
#undef LDA_
#undef LDB_
#undef MFMA_

    // ---- fused epilogue (unchanged math) ----
    #pragma unroll
    for (int i = 0; i < 4; ++i) {
        #pragma unroll
        for (int reg = 0; reg < 4; ++reg) {
            int m = m0 + wrow * 64 + i * 16 + (lane >> 4) * 4 + reg;
            float rv = rsqrtf(rrms_acc[m] * (1.0f / H_) + EPS_);
            #pragma unroll
            for (int j = 0; j < 4; ++j) {
                int n = n0 + wcol * 64 + j * 16 + (lane & 15);
                float go = acc[i][j][reg];
                float ov = bf2f(Abuf[(size_t)m * K2_ + n]);   // bf16 o
                out[(size_t)m * H_ + n] = ov * rv * gw[n] * go * sigmoidf_(go);
            }
        }
    }
}

// ---------------------------------------------------------------------------
extern "C" void kernel_launch(void* const* d_in, const int* in_sizes, int n_in,
                              void* d_out, int out_size, void* d_ws, size_t ws_size,
                              hipStream_t stream) {
    (void)in_sizes; (void)n_in; (void)out_size; (void)ws_size;
    const float* x   = (const float*)d_in[0];
    const float* Wq  = (const float*)d_in[1];
    const float* Wk  = (const float*)d_in[2];
    const float* Wog = (const float*)d_in[3];
    const float* Wig = (const float*)d_in[4];
    const float* gw  = (const float*)d_in[5];
    float* out = (float*)d_out;

    const size_t MK = (size_t)B_ * L_ * KD_;               // 524288
    unsigned short* Abuf = (unsigned short*)d_ws;          // [4096][4096] bf16
    unsigned short* Bbuf = Abuf + (size_t)4096 * K2_;      // [2048][4096] bf16
    unsigned short* qt_b = Bbuf + (size_t)2048 * K2_;      // [4096][128] bf16
    unsigned short* kA_b = qt_b + MK;
    unsigned short* kB_b = kA_b + MK;
    unsigned short* Wqk  = kB_b + MK;                      // [256][2048] bf16
    unsigned short* Pbuf = Wqk + (size_t)256 * H_;         // [64][64][128] bf16
    float* partial  = (float*)(Pbuf + (size_t)64 * 64 * 128);  // [4][4096][256]
    float* rrms_acc = partial + (size_t)4 * 4096 * 256;    // [4096] fp32
    // ws use: 48 MB bf16 GEMM bufs + 3 MB qk + 1 MB W + 1 MB P + 16 MB partial

    prep_all<<<JOBA_BLKS + JOBB_BLKS + JOBC_BLKS, 256, 0, stream>>>(
        x, Wq, Wk, Wog, Wig, Abuf, Wqk, Bbuf, rrms_acc);
    qk_proj_mfma<<<256, 512, 0, stream>>>(Abuf, Wqk, partial);
    scan_scale_kernel<<<dim3(32, B_, 4), 256, 0, stream>>>(partial, qt_b, kA_b, kB_b);
    p_kernel<<<dim3(32, B_), 256, 0, stream>>>(qt_b, kA_b, kB_b, Pbuf);
    pv_kernel<<<dim3(32, B_, 16), 256, 0, stream>>>(Pbuf, Abuf, rrms_acc);
    out_gemm_mfma<<<256, 512, 0, stream>>>(Abuf, Bbuf, gw, rrms_acc, out);
}